// Round 1
// 880.794 us; speedup vs baseline: 1.1674x; 1.1674x over previous
//
#include <hip/hip_runtime.h>
#include <math.h>

// FNO1d: B=64, N=8192, F_IN=2, W=64, L=5, M=16, PAD=9 -> NLEN=8201
#define SROW 8224      // row stride: 8224*4 = 32896 B, 128B-aligned rows
#define NLEN 8201
#define NB 64
#define W 64
#define M 16
#define NL 5
#define TWO_PI 6.283185307179586476925286766559
#define NT_STAT 514    // static B-frag n-tiles (n < 8224); OOB tiles clamp here

typedef unsigned short u16;
typedef __attribute__((ext_vector_type(8))) short bf16x8;   // MFMA A/B frag (4 VGPR)
typedef __attribute__((ext_vector_type(4))) float f32x4;    // MFMA C/D frag
typedef __attribute__((ext_vector_type(4))) short short4v;

// ---- bf16 split-precision helpers (x = hi + lo, both RN bf16) ----
__device__ __forceinline__ u16 bf16rn(float x) {
    unsigned u = __float_as_uint(x);
    unsigned r = (u + 0x7fffu + ((u >> 16) & 1u)) >> 16;
    return (u16)r;
}
__device__ __forceinline__ float bf16tof(u16 h) {
    return __uint_as_float(((unsigned)h) << 16);
}
__device__ __forceinline__ void bf16split(float x, u16& h, u16& lo) {
    h = bf16rn(x);
    lo = bf16rn(x - bf16tof(h));
}

// Both MFMA operand sides use the SAME (lane>>4, e) -> kk bijection, so the
// hardware's exact within-K ordering cancels out of the contraction:
//   kk(g, e) = g*4 + (e&3) + 16*(e>>2),  lane = (idx&15) + 16*((kk&15)>>2)

// Branchless gelu: A&S 7.1.26 erf (|err| <= 1.5e-7), rcp+exp2 fast paths.
__device__ __forceinline__ float gelu_f(float x) {
    float s = x * 0.70710678118654752f;
    float a = fabsf(s);
    float t = __builtin_amdgcn_rcpf(fmaf(0.3275911f, a, 1.0f));
    float p = fmaf(1.061405429f, t, -1.453152027f);
    p = fmaf(p, t, 1.421413741f);
    p = fmaf(p, t, -0.284496736f);
    p = fmaf(p, t, 0.254829592f);
    p = p * t;
    float e = __expf(-a * a);
    float er = copysignf(fmaf(-p, e, 1.0f), s);
    float h = 0.5f * x;
    return fmaf(h, er, h);
}

// async global->LDS, 16B per lane (used by kproj)
__device__ __forceinline__ void gld16(const float* g, float* l) {
    __builtin_amdgcn_global_load_lds(
        (const __attribute__((address_space(1))) void*)g,
        (__attribute__((address_space(3))) void*)l, 16, 0, 0);
}

// Twiddle tables cosT[k][n], sinT[k][n] (fp64-accurate), k = 0..15.
__global__ void ktable(float* __restrict__ cosT, float* __restrict__ sinT) {
    int n = blockIdx.x * 256 + threadIdx.x;
    int k = blockIdx.y;
    if (n >= SROW) return;
    long long m = ((long long)k * (long long)n) % NLEN;
    double th = (TWO_PI / (double)NLEN) * (double)m;
    double sv, cv;
    sincos(th, &sv, &cv);
    cosT[k * SROW + n] = (float)cv;
    sinT[k * SROW + n] = (float)sv;
}

// Static B-frags for kstep 2 (U rows 64..95 = [cos1..15 | sin1..15 | ones | zero]).
// Ustat[hl][nt][lane][e] bf16; built once, L2/L3-resident (~1 MB).
__global__ __launch_bounds__(256) void kstat(u16* __restrict__ Ustat) {
    int nt = blockIdx.x;             // 0..NT_STAT-1
    int t = threadIdx.x;
    for (int s = t; s < 512; s += 256) {
        int lane = s >> 3, e = s & 7;
        int kk = ((lane >> 4) << 2) + (e & 3) + ((e >> 2) << 4);
        int r = 64 + kk;
        int n = nt * 16 + (lane & 15);
        float val;
        if (r < 94) {
            int k = (r < 79) ? (r - 63) : (r - 78);
            long long mm = ((long long)k * (long long)n) % NLEN;
            double th = (TWO_PI / (double)NLEN) * (double)mm;
            double sv, cv;
            sincos(th, &sv, &cv);
            val = (float)((r < 79) ? cv : sv);
        } else {
            val = (r == 94) ? 1.0f : 0.0f;
        }
        u16 h, lo;
        bf16split(val, h, lo);
        size_t base = ((size_t)nt * 64 + lane) * 8 + e;
        Ustat[base] = h;
        Ustat[(size_t)NT_STAT * 512 + base] = lo;
    }
}

// Pack cw (all 5 layers) into A-frags: AcwBuf[l][ks(2)][hl(2)][mt(4)][lane][e].
// A[m=o][k] = cw[l][o][k]  (rows 0..63 of the 96-row weight matrix).
__global__ __launch_bounds__(256) void kprep(const float* __restrict__ cw,
                                             u16* __restrict__ AcwBuf) {
    int l = blockIdx.x;
    int t = threadIdx.x;
    const float* cwl = cw + (size_t)l * W * W;
    u16* ob = AcwBuf + (size_t)l * 8192;
    for (int s = t; s < 4096; s += 256) {
        int e = s & 7, lane = (s >> 3) & 63, mt = (s >> 9) & 3, ks = s >> 11;
        int kk = ((lane >> 4) << 2) + (e & 3) + ((e >> 2) << 4);
        int k = ks * 32 + kk;
        int o = mt * 16 + (lane & 15);
        u16 h, lo;
        bf16split(cwl[o * 64 + k], h, lo);
        ob[(((size_t)ks * 2 + 0) * 4 + mt) * 512 + lane * 8 + e] = h;
        ob[(((size_t)ks * 2 + 1) * 4 + mt) * 512 + lane * 8 + e] = lo;
    }
}

// Lift: v[b][w][n] = x[b][n][:]@lift_w + lift_b, 0 in pad. 4 cols/thread, float4 I/O.
__global__ __launch_bounds__(256) void klift(const float* __restrict__ x,
        const float* __restrict__ lw, const float* __restrict__ lb,
        float* __restrict__ v) {
    int n4 = blockIdx.x * 256 + threadIdx.x;
    int b = blockIdx.y;
    if (n4 >= 2056) return;
    int n = n4 * 4;
    bool in = (n < 8192);
    float4 xa = {0.f, 0.f, 0.f, 0.f}, xb = {0.f, 0.f, 0.f, 0.f};
    if (in) {
        const float* xp = x + ((size_t)b * 8192 + n) * 2;
        xa = *(const float4*)xp;
        xb = *(const float4*)(xp + 4);
    }
    float* vp = v + (size_t)b * W * SROW + n;
    #pragma unroll
    for (int w = 0; w < W; w++) {
        float4 o4 = {0.f, 0.f, 0.f, 0.f};
        if (in) {
            float l0 = lw[w], l1 = lw[W + w], bb = lb[w];
            o4.x = fmaf(xa.x, l0, fmaf(xa.y, l1, bb));
            o4.y = fmaf(xa.z, l0, fmaf(xa.w, l1, bb));
            o4.z = fmaf(xb.x, l0, fmaf(xb.y, l1, bb));
            o4.w = fmaf(xb.z, l0, fmaf(xb.w, l1, bb));
        }
        *(float4*)(vp + (size_t)w * SROW) = o4;
    }
}

// Forward DFT, 16 modes. 2 rows/block (2048 blocks), LOW-VGPR strided loop.
__global__ __launch_bounds__(256) void kdft(const float* __restrict__ v,
        const float* __restrict__ cosT, const float* __restrict__ sinT,
        float* __restrict__ F) {
    int row0 = blockIdx.x * 2;
    int t = threadIdx.x;
    float accR[2][16], accI[2][16];
    #pragma unroll
    for (int r = 0; r < 2; r++)
        #pragma unroll
        for (int k = 0; k < 16; k++) { accR[r][k] = 0.f; accI[r][k] = 0.f; }
    const float* v0 = v + (size_t)row0 * SROW;

    for (int c = t; c < 2050; c += 256) {
        int n = c << 2;
        float4 c1 = *(const float4*)(cosT + SROW + n);
        float4 s1 = *(const float4*)(sinT + SROW + n);
        float4 va = *(const float4*)(v0 + n);
        float4 vb = *(const float4*)(v0 + SROW + n);
        accR[0][0] += (va.x + va.y) + (va.z + va.w);
        accR[1][0] += (vb.x + vb.y) + (vb.z + vb.w);
        float4 ck = c1, sk = s1;
        #pragma unroll
        for (int k = 1; k < 16; k++) {
            float a0 = accR[0][k];
            a0 = fmaf(va.x, ck.x, a0); a0 = fmaf(va.y, ck.y, a0);
            a0 = fmaf(va.z, ck.z, a0); a0 = fmaf(va.w, ck.w, a0);
            accR[0][k] = a0;
            float b0 = accI[0][k];
            b0 = fmaf(-va.x, sk.x, b0); b0 = fmaf(-va.y, sk.y, b0);
            b0 = fmaf(-va.z, sk.z, b0); b0 = fmaf(-va.w, sk.w, b0);
            accI[0][k] = b0;
            float a1 = accR[1][k];
            a1 = fmaf(vb.x, ck.x, a1); a1 = fmaf(vb.y, ck.y, a1);
            a1 = fmaf(vb.z, ck.z, a1); a1 = fmaf(vb.w, ck.w, a1);
            accR[1][k] = a1;
            float b1 = accI[1][k];
            b1 = fmaf(-vb.x, sk.x, b1); b1 = fmaf(-vb.y, sk.y, b1);
            b1 = fmaf(-vb.z, sk.z, b1); b1 = fmaf(-vb.w, sk.w, b1);
            accI[1][k] = b1;
            if (k < 15) {
                float4 cn, sn;
                cn.x = fmaf(ck.x, c1.x, -sk.x * s1.x); sn.x = fmaf(ck.x, s1.x, sk.x * c1.x);
                cn.y = fmaf(ck.y, c1.y, -sk.y * s1.y); sn.y = fmaf(ck.y, s1.y, sk.y * c1.y);
                cn.z = fmaf(ck.z, c1.z, -sk.z * s1.z); sn.z = fmaf(ck.z, s1.z, sk.z * c1.z);
                cn.w = fmaf(ck.w, c1.w, -sk.w * s1.w); sn.w = fmaf(ck.w, s1.w, sk.w * c1.w);
                ck = cn; sk = sn;
            }
        }
    }

    if (t == 0) {        // tail n = 8200
        int n = 8200;
        #pragma unroll
        for (int k = 0; k < 16; k++) {
            float cv = cosT[(size_t)k * SROW + n], sv = sinT[(size_t)k * SROW + n];
            float v0r = v0[n], v1r = v0[SROW + n];
            accR[0][k] = fmaf(v0r, cv, accR[0][k]);
            accI[0][k] = fmaf(-v0r, sv, accI[0][k]);
            accR[1][k] = fmaf(v1r, cv, accR[1][k]);
            accI[1][k] = fmaf(-v1r, sv, accI[1][k]);
        }
    }

    #pragma unroll
    for (int r = 0; r < 2; r++)
        #pragma unroll
        for (int k = 0; k < 16; k++) {
            float xr = accR[r][k], xi = accI[r][k];
            #pragma unroll
            for (int off = 32; off > 0; off >>= 1) {
                xr += __shfl_down(xr, off, 64);
                xi += __shfl_down(xi, off, 64);
            }
            accR[r][k] = xr; accI[r][k] = xi;
        }
    __shared__ float red[4][64];
    int lane = t & 63, wv = t >> 6;
    if (lane == 0) {
        #pragma unroll
        for (int r = 0; r < 2; r++)
            #pragma unroll
            for (int k = 0; k < 16; k++) {
                red[wv][r * 32 + 2 * k]     = accR[r][k];
                red[wv][r * 32 + 2 * k + 1] = accI[r][k];
            }
    }
    __syncthreads();
    if (t < 64) {
        float sum = red[0][t] + red[1][t] + red[2][t] + red[3][t];
        int r = t >> 5, rem = t & 31, k = rem >> 1, comp = rem & 1;
        F[(((size_t)(row0 + r)) * M + k) * 2 + comp] = sum;
    }
}

// Write one W-matrix value (row 64+kk, col o) into per-b ks2 A-frags (hi+lo).
__device__ __forceinline__ void wfrag(u16* wb2, int mt, int kk, int ol, float val) {
    int lane = ol + (((kk & 15) >> 2) << 4);
    int e = (kk & 3) + ((kk >> 4) << 2);
    u16 h, lo;
    bf16split(val, h, lo);
    wb2[(size_t)mt * 512 + lane * 8 + e] = h;
    wb2[(size_t)(4 + mt) * 512 + lane * 8 + e] = lo;
}

// Mode mix: P[o][k] = sum_i F[i][k] * kern[i][o][k]; emit spectral rows 64..95
// of the weight matrix directly as MFMA A-fragments WfA2[b][hl][mt][lane][e].
__global__ __launch_bounds__(256) void kmix(const float* __restrict__ F,
        const float* __restrict__ kr, const float* __restrict__ ki,
        const float* __restrict__ cb, u16* __restrict__ WfA2, int l) {
    int b = blockIdx.x, kg = blockIdx.y;
    int t = threadIdx.x;
    int o = t & 63, ii = t >> 6;
    const float* fb = F + (size_t)b * W * M * 2;
    const float* krl = kr + (size_t)l * W * W * M;
    const float* kil = ki + (size_t)l * W * W * M;
    float pr[4] = {0.f, 0.f, 0.f, 0.f}, pi[4] = {0.f, 0.f, 0.f, 0.f};
    for (int i = ii * 16; i < ii * 16 + 16; i++) {
        float4 kr4 = *(const float4*)(krl + ((size_t)i * W + o) * M + kg * 4);
        float4 ki4 = *(const float4*)(kil + ((size_t)i * W + o) * M + kg * 4);
        float4 f0 = *(const float4*)(fb + ((size_t)i * M + kg * 4) * 2);
        float4 f1 = *(const float4*)(fb + ((size_t)i * M + kg * 4) * 2 + 4);
        pr[0] += f0.x * kr4.x - f0.y * ki4.x;  pi[0] += f0.x * ki4.x + f0.y * kr4.x;
        pr[1] += f0.z * kr4.y - f0.w * ki4.y;  pi[1] += f0.z * ki4.y + f0.w * kr4.y;
        pr[2] += f1.x * kr4.z - f1.y * ki4.z;  pi[2] += f1.x * ki4.z + f1.y * kr4.z;
        pr[3] += f1.z * kr4.w - f1.w * ki4.w;  pi[3] += f1.z * ki4.w + f1.w * kr4.w;
    }
    __shared__ float red[4][64][8];
    #pragma unroll
    for (int c = 0; c < 4; c++) {
        red[ii][o][2 * c]     = pr[c];
        red[ii][o][2 * c + 1] = pi[c];
    }
    __syncthreads();
    if (ii == 0) {
        u16* wb2 = WfA2 + (size_t)b * 4096;
        int mt = o >> 4, ol = o & 15;
        #pragma unroll
        for (int c = 0; c < 4; c++) {
            int k = kg * 4 + c;
            float sr = red[0][o][2 * c] + red[1][o][2 * c] + red[2][o][2 * c] + red[3][o][2 * c];
            float si = red[0][o][2 * c + 1] + red[1][o][2 * c + 1] + red[2][o][2 * c + 1] + red[3][o][2 * c + 1];
            if (k == 0) {
                wfrag(wb2, mt, 30, ol, cb[l * W + o] + sr * (1.0f / (float)NLEN));
                wfrag(wb2, mt, 31, ol, 0.0f);
            } else {
                wfrag(wb2, mt, k - 1,  ol, sr * (2.0f / (float)NLEN));
                wfrag(wb2, mt, 14 + k, ol, -si * (2.0f / (float)NLEN));
            }
        }
    }
}

// Fused conv + inverse transform + gelu via bf16-split MFMA, IN-PLACE.
// Per b: OUT[64o x 8224n] = Wmat[64x96] @ U[96xN]; 4 products hh+hl+lh+ll.
// Block: 512 thr = 8 waves; tile 64o x 256n; wave w owns n in [32w, 32w+32).
// Dynamic U (v rows 0..63) converted to hi/lo frags in 64 KB LDS; static rows
// 64..95 come prepacked from Ustat; A-frags from AcwL (cw) + WfA2 (spectral).
__global__ __launch_bounds__(512, 4) void kconv(float* __restrict__ v,
        const u16* __restrict__ AcwL, const u16* __restrict__ WfA2,
        const u16* __restrict__ Ustat) {
    __shared__ __align__(16) u16 fragU[2][2][16][64][8];   // [ks][hl][nt][lane][e]
    int t = threadIdx.x;
    int b = blockIdx.y;
    int n0 = blockIdx.x * 256;
    int lane = t & 63;
    int wv = __builtin_amdgcn_readfirstlane(t >> 6);       // 0..7
    float* vb = v + (size_t)b * W * SROW;

    // ---- load 64 v-rows x 256 cols, split to bf16 hi/lo frags in LDS ----
    {
        int col = t & 255;
        int half = t >> 8;                 // 0/1
        int nt = col >> 4;
        int lt = col & 15;
        #pragma unroll
        for (int q = 0; q < 8; q++) {
            int quad = q * 2 + half;       // 0..15 -> rows 4q..4q+3
            const float* src = vb + (size_t)(quad * 4) * SROW + n0 + col;
            float x0 = src[0];
            float x1 = src[SROW];
            float x2 = src[2 * SROW];
            float x3 = src[3 * SROW];
            int ks = quad >> 3;
            int laneT = lt + ((quad & 3) << 4);
            int e0 = ((quad >> 2) & 1) << 2;
            u16 h0, l0, h1, l1, h2, l2, h3, l3;
            bf16split(x0, h0, l0); bf16split(x1, h1, l1);
            bf16split(x2, h2, l2); bf16split(x3, h3, l3);
            short4v hv = {(short)h0, (short)h1, (short)h2, (short)h3};
            short4v lv = {(short)l0, (short)l1, (short)l2, (short)l3};
            *(short4v*)&fragU[ks][0][nt][laneT][e0] = hv;
            *(short4v*)&fragU[ks][1][nt][laneT][e0] = lv;
        }
    }

    f32x4 acc[4][2];
    #pragma unroll
    for (int mt = 0; mt < 4; mt++)
        #pragma unroll
        for (int j = 0; j < 2; j++)
            acc[mt][j] = (f32x4){0.f, 0.f, 0.f, 0.f};

    __syncthreads();

    const u16* wb2 = WfA2 + (size_t)b * 4096;
    int nt0 = wv * 2;
    #pragma unroll
    for (int ks = 0; ks < 3; ks++) {
        const u16* ab = (ks < 2) ? (AcwL + (size_t)ks * 4096) : wb2;
        bf16x8 Ah[4], Al[4];
        #pragma unroll
        for (int mt = 0; mt < 4; mt++) {
            Ah[mt] = *(const bf16x8*)(ab + (size_t)mt * 512 + lane * 8);
            Al[mt] = *(const bf16x8*)(ab + (size_t)(4 + mt) * 512 + lane * 8);
        }
        #pragma unroll
        for (int ntl = 0; ntl < 2; ntl++) {
            bf16x8 Bh, Bl;
            if (ks < 2) {
                Bh = *(const bf16x8*)&fragU[ks][0][nt0 + ntl][lane][0];
                Bl = *(const bf16x8*)&fragU[ks][1][nt0 + ntl][lane][0];
            } else {
                int ntg = (n0 >> 4) + nt0 + ntl;
                if (ntg >= NT_STAT) ntg = NT_STAT - 1;   // OOB cols: any finite data
                Bh = *(const bf16x8*)(Ustat + ((size_t)ntg * 64 + lane) * 8);
                Bl = *(const bf16x8*)(Ustat + (size_t)NT_STAT * 512 + ((size_t)ntg * 64 + lane) * 8);
            }
            #pragma unroll
            for (int mt = 0; mt < 4; mt++) {
                acc[mt][ntl] = __builtin_amdgcn_mfma_f32_16x16x32_bf16(Ah[mt], Bh, acc[mt][ntl], 0, 0, 0);
                acc[mt][ntl] = __builtin_amdgcn_mfma_f32_16x16x32_bf16(Ah[mt], Bl, acc[mt][ntl], 0, 0, 0);
                acc[mt][ntl] = __builtin_amdgcn_mfma_f32_16x16x32_bf16(Al[mt], Bh, acc[mt][ntl], 0, 0, 0);
                acc[mt][ntl] = __builtin_amdgcn_mfma_f32_16x16x32_bf16(Al[mt], Bl, acc[mt][ntl], 0, 0, 0);
            }
        }
    }

    // ---- epilogue: gelu + store. D: col = lane&15, row = (lane>>4)*4 + reg ----
    int r4 = (lane >> 4) << 2;
    #pragma unroll
    for (int ntl = 0; ntl < 2; ntl++) {
        int n = n0 + wv * 32 + ntl * 16 + (lane & 15);
        if (n < SROW) {
            #pragma unroll
            for (int mt = 0; mt < 4; mt++) {
                float* vo = vb + (size_t)(mt * 16 + r4) * SROW + n;
                vo[0]        = gelu_f(acc[mt][ntl][0]);
                vo[SROW]     = gelu_f(acc[mt][ntl][1]);
                vo[2 * SROW] = gelu_f(acc[mt][ntl][2]);
                vo[3 * SROW] = gelu_f(acc[mt][ntl][3]);
            }
        }
    }
}

// Final projection: 1024 threads = 16 waves; wave w owns h rows [8w,8w+8).
__global__ __launch_bounds__(1024, 8) void kproj(const float* __restrict__ v,
        const float* __restrict__ w1, const float* __restrict__ b1,
        const float* __restrict__ w2, const float* __restrict__ b2,
        float* __restrict__ out) {
    __shared__ __align__(16) float U[2][8][256];
    __shared__ __align__(16) float red[16][256];
    int t = threadIdx.x;
    int b = blockIdx.y;
    int n0 = blockIdx.x * 256;
    int lane = t & 63;
    int wvu = __builtin_amdgcn_readfirstlane(t >> 6);
    const float* vb = v + (size_t)b * (W * SROW);
    int colf = n0 + lane * 4;
    int h0 = wvu * 8;

    if (wvu < 8) gld16(vb + (size_t)wvu * SROW + colf, &U[0][wvu][0]);

    float acc[8][4];
    #pragma unroll
    for (int r = 0; r < 8; r++) {
        float bs = b1[h0 + r];
        acc[r][0] = acc[r][1] = acc[r][2] = acc[r][3] = bs;
    }
    __syncthreads();

    int buf = 0;
    for (int c = 0; c < 8; c++) {
        if (c < 7 && wvu < 8)
            gld16(vb + (size_t)((c + 1) * 8 + wvu) * SROW + colf, &U[buf ^ 1][wvu][0]);
        #pragma unroll
        for (int kk = 0; kk < 8; kk++) {
            int k = c * 8 + kk;
            float4 u = *(const float4*)&U[buf][kk][lane * 4];
            const float* wk = w1 + k * 128 + h0;
            #pragma unroll
            for (int r = 0; r < 8; r++) {
                float wr = wk[r];
                acc[r][0] = fmaf(wr, u.x, acc[r][0]);
                acc[r][1] = fmaf(wr, u.y, acc[r][1]);
                acc[r][2] = fmaf(wr, u.z, acc[r][2]);
                acc[r][3] = fmaf(wr, u.w, acc[r][3]);
            }
        }
        if (c < 7) { __syncthreads(); buf ^= 1; }
    }

    float p0 = 0.f, p1 = 0.f, p2 = 0.f, p3 = 0.f;
    #pragma unroll
    for (int r = 0; r < 8; r++) {
        float wh = w2[h0 + r];
        p0 = fmaf(gelu_f(acc[r][0]), wh, p0);
        p1 = fmaf(gelu_f(acc[r][1]), wh, p1);
        p2 = fmaf(gelu_f(acc[r][2]), wh, p2);
        p3 = fmaf(gelu_f(acc[r][3]), wh, p3);
    }
    float4 p4 = {p0, p1, p2, p3};
    *(float4*)&red[wvu][lane * 4] = p4;
    __syncthreads();
    if (t < 256) {
        float s = b2[0];
        #pragma unroll
        for (int w = 0; w < 16; w++) s += red[w][t];
        out[(size_t)b * 8192 + n0 + t] = s;
    }
}

extern "C" void kernel_launch(void* const* d_in, const int* in_sizes, int n_in,
                              void* d_out, int out_size, void* d_ws, size_t ws_size,
                              hipStream_t stream) {
    const float* x  = (const float*)d_in[0];
    const float* lw = (const float*)d_in[1];
    const float* lb = (const float*)d_in[2];
    const float* kr = (const float*)d_in[3];
    const float* ki = (const float*)d_in[4];
    const float* cw = (const float*)d_in[5];
    const float* cb = (const float*)d_in[6];
    const float* w1 = (const float*)d_in[7];
    const float* b1 = (const float*)d_in[8];
    const float* w2 = (const float*)d_in[9];
    const float* b2 = (const float*)d_in[10];
    float* out = (float*)d_out;

    // workspace (floats): v 33,685,504 | cosT/sinT 131,584 ea | F 131,072 |
    // then u16 planes: Ustat 526,336 | AcwBuf 40,960 | WfA2 262,144  => ~138.0 MB
    float* ws = (float*)d_ws;
    size_t vsz = (size_t)NB * W * SROW;
    float* v    = ws;
    float* cosT = v + vsz;
    float* sinT = cosT + (size_t)16 * SROW;
    float* F    = sinT + (size_t)16 * SROW;
    u16* Ustat  = (u16*)(F + (size_t)NB * W * M * 2);
    u16* AcwBuf = Ustat + (size_t)2 * NT_STAT * 512;
    u16* WfA2   = AcwBuf + (size_t)NL * 8192;

    ktable<<<dim3(33, 16), 256, 0, stream>>>(cosT, sinT);
    kstat<<<dim3(NT_STAT), 256, 0, stream>>>(Ustat);
    kprep<<<dim3(NL), 256, 0, stream>>>(cw, AcwBuf);
    klift<<<dim3(9, NB), 256, 0, stream>>>(x, lw, lb, v);

    for (int l = 0; l < NL; l++) {
        kdft<<<NB * W / 2, 256, 0, stream>>>(v, cosT, sinT, F);
        kmix<<<dim3(NB, 4), 256, 0, stream>>>(F, kr, ki, cb, WfA2, l);
        kconv<<<dim3(33, NB), 512, 0, stream>>>(v, AcwBuf + (size_t)l * 8192, WfA2, Ustat);
    }
    kproj<<<dim3(32, NB), 1024, 0, stream>>>(v, w1, b1, w2, b2, out);
}

// Round 2
// 768.943 us; speedup vs baseline: 1.3372x; 1.1455x over previous
//
#include <hip/hip_runtime.h>
#include <math.h>

// FNO1d: B=64, N=8192, F_IN=2, W=64, L=5, M=16, PAD=9 -> NLEN=8201
#define SROW 8224      // row stride: 8224*4 = 32896 B, 128B-aligned rows
#define NLEN 8201
#define NB 64
#define W 64
#define M 16
#define NL 5
#define TWO_PI 6.283185307179586476925286766559
#define NT_STAT 514    // static B-frag n-tiles (n < 8224); OOB tiles clamp here
#define NSTEPS 257     // DFT twiddle A-frag K-steps of 32 (covers n < 8224)

typedef unsigned short u16;
typedef __attribute__((ext_vector_type(8))) short bf16x8;   // MFMA A/B frag (4 VGPR)
typedef __attribute__((ext_vector_type(4))) float f32x4;    // MFMA C/D frag
typedef __attribute__((ext_vector_type(4))) short short4v;

// ---- bf16 split-precision helpers (x = hi + lo, both RN bf16) ----
__device__ __forceinline__ u16 bf16rn(float x) {
    unsigned u = __float_as_uint(x);
    unsigned r = (u + 0x7fffu + ((u >> 16) & 1u)) >> 16;
    return (u16)r;
}
__device__ __forceinline__ float bf16tof(u16 h) {
    return __uint_as_float(((unsigned)h) << 16);
}
__device__ __forceinline__ void bf16split(float x, u16& h, u16& lo) {
    h = bf16rn(x);
    lo = bf16rn(x - bf16tof(h));
}

// Both MFMA operand sides always use the SAME (lane>>4, e) -> kk bijection, so
// the hardware's exact within-K ordering cancels out of every contraction.
//   main GEMM:     kk(g,e) = g*4 + (e&3) + 16*(e>>2)
//   DFT epilogue:  nloc(g,e) = g*8 + e

// Branchless gelu: A&S 7.1.26 erf (|err| <= 1.5e-7), rcp+exp fast paths.
__device__ __forceinline__ float gelu_f(float x) {
    float s = x * 0.70710678118654752f;
    float a = fabsf(s);
    float t = __builtin_amdgcn_rcpf(fmaf(0.3275911f, a, 1.0f));
    float p = fmaf(1.061405429f, t, -1.453152027f);
    p = fmaf(p, t, 1.421413741f);
    p = fmaf(p, t, -0.284496736f);
    p = fmaf(p, t, 0.254829592f);
    p = p * t;
    float e = __expf(-a * a);
    float er = copysignf(fmaf(-p, e, 1.0f), s);
    float h = 0.5f * x;
    return fmaf(h, er, h);
}

// async global->LDS, 16B per lane (used by kproj)
__device__ __forceinline__ void gld16(const float* g, float* l) {
    __builtin_amdgcn_global_load_lds(
        (const __attribute__((address_space(1))) void*)g,
        (__attribute__((address_space(3))) void*)l, 16, 0, 0);
}

// Static B-frags for main-GEMM ks=2 (U rows 64..95 = [cos1..15|sin1..15|1|0]).
__global__ __launch_bounds__(256) void kstat(u16* __restrict__ Ustat) {
    int nt = blockIdx.x;             // 0..NT_STAT-1
    int t = threadIdx.x;
    for (int s = t; s < 512; s += 256) {
        int lane = s >> 3, e = s & 7;
        int kk = ((lane >> 4) << 2) + (e & 3) + ((e >> 2) << 4);
        int r = 64 + kk;
        int n = nt * 16 + (lane & 15);
        float val;
        if (r < 94) {
            int k = (r < 79) ? (r - 63) : (r - 78);
            long long mm = ((long long)k * (long long)n) % NLEN;
            double th = (TWO_PI / (double)NLEN) * (double)mm;
            double sv, cv;
            sincos(th, &sv, &cv);
            val = (float)((r < 79) ? cv : sv);
        } else {
            val = (r == 94) ? 1.0f : 0.0f;
        }
        u16 h, lo;
        bf16split(val, h, lo);
        size_t base = ((size_t)nt * 64 + lane) * 8 + e;
        Ustat[base] = h;
        Ustat[(size_t)NT_STAT * 512 + base] = lo;
    }
}

// Twiddle A-frags for the fused DFT: Tdft[nstep][kcT(2)][hl(2)][lane][e].
// A[m=kc][n]: kc<16 -> cos(2pi*kc*n/NLEN); kc>=16 -> -sin(2pi*(kc-16)*n/NLEN).
// logical n position: nloc(g,e) = g*8 + e, n = nstep*32 + nloc.
__global__ __launch_bounds__(256) void kdtab(u16* __restrict__ Tdft) {
    int nstep = blockIdx.x;
    int t = threadIdx.x;
    for (int s = t; s < 1024; s += 256) {     // kcT(2) x lane(64) x e(8)
        int e = s & 7, lane = (s >> 3) & 63, kcT = s >> 9;
        int kc = kcT * 16 + (lane & 15);
        int n = nstep * 32 + ((lane >> 4) << 3) + e;
        int k = kc & 15;
        long long m = ((long long)k * (long long)n) % NLEN;
        double th = (TWO_PI / (double)NLEN) * (double)m;
        double sv, cv;
        sincos(th, &sv, &cv);
        float val = (kc < 16) ? (float)cv : (float)(-sv);
        u16 h, lo;
        bf16split(val, h, lo);
        size_t base = (((size_t)nstep * 2 + kcT) * 2) * 512 + lane * 8 + e;
        Tdft[base] = h;
        Tdft[base + 512] = lo;
    }
}

// Pack cw (all 5 layers) into A-frags: AcwBuf[l][ks(2)][hl(2)][mt(4)][lane][e].
__global__ __launch_bounds__(256) void kprep(const float* __restrict__ cw,
                                             u16* __restrict__ AcwBuf) {
    int l = blockIdx.x;
    int t = threadIdx.x;
    const float* cwl = cw + (size_t)l * W * W;
    u16* ob = AcwBuf + (size_t)l * 8192;
    for (int s = t; s < 4096; s += 256) {
        int e = s & 7, lane = (s >> 3) & 63, mt = (s >> 9) & 3, ks = s >> 11;
        int kk = ((lane >> 4) << 2) + (e & 3) + ((e >> 2) << 4);
        int k = ks * 32 + kk;
        int o = mt * 16 + (lane & 15);
        u16 h, lo;
        bf16split(cwl[o * 64 + k], h, lo);
        ob[(((size_t)ks * 2 + 0) * 4 + mt) * 512 + lane * 8 + e] = h;
        ob[(((size_t)ks * 2 + 1) * 4 + mt) * 512 + lane * 8 + e] = lo;
    }
}

// Lift: v[b][w][n] = x[b][n][:]@lift_w + lift_b, 0 in pad. 4 cols/thread.
__global__ __launch_bounds__(256) void klift(const float* __restrict__ x,
        const float* __restrict__ lw, const float* __restrict__ lb,
        float* __restrict__ v) {
    int n4 = blockIdx.x * 256 + threadIdx.x;
    int b = blockIdx.y;
    if (n4 >= 2056) return;
    int n = n4 * 4;
    bool in = (n < 8192);
    float4 xa = {0.f, 0.f, 0.f, 0.f}, xb = {0.f, 0.f, 0.f, 0.f};
    if (in) {
        const float* xp = x + ((size_t)b * 8192 + n) * 2;
        xa = *(const float4*)xp;
        xb = *(const float4*)(xp + 4);
    }
    float* vp = v + (size_t)b * W * SROW + n;
    #pragma unroll
    for (int w = 0; w < W; w++) {
        float4 o4 = {0.f, 0.f, 0.f, 0.f};
        if (in) {
            float l0 = lw[w], l1 = lw[W + w], bb = lb[w];
            o4.x = fmaf(xa.x, l0, fmaf(xa.y, l1, bb));
            o4.y = fmaf(xa.z, l0, fmaf(xa.w, l1, bb));
            o4.z = fmaf(xb.x, l0, fmaf(xb.y, l1, bb));
            o4.w = fmaf(xb.z, l0, fmaf(xb.w, l1, bb));
        }
        *(float4*)(vp + (size_t)w * SROW) = o4;
    }
}

// Standalone MFMA DFT (layer-0): Fpart[b][grp][kc32][o64] partials over the
// grp's n-chunks. Grid (NB, 4), 512 thr. v staged as bf16 hi/lo B-frags in
// swizzled per-wave LDS regions; Tdft supplies A; dacc accumulates over chunks.
__global__ __launch_bounds__(512, 4) void kdft2(const float* __restrict__ v,
        const u16* __restrict__ Tdft, float* __restrict__ Fpart, int fstride) {
    __shared__ __align__(16) u16 outT[8 * 4096];   // 64 KB: 8 wave-regions
    int t = threadIdx.x;
    int b = blockIdx.x, grp = blockIdx.y;
    int lane = t & 63;
    int wv = __builtin_amdgcn_readfirstlane(t >> 6);
    const float* vb = v + (size_t)b * W * SROW;

    f32x4 dacc[2][4];
    #pragma unroll
    for (int kt = 0; kt < 2; kt++)
        #pragma unroll
        for (int ot = 0; ot < 4; ot++) dacc[kt][ot] = (f32x4){0.f, 0.f, 0.f, 0.f};

    int cl = t & 255, half = t >> 8;
    int wvD = cl >> 5, nl = cl & 31;
    u16* wr = outT + wvD * 4096;
    int g = lane >> 4;

    for (int c = grp; c < 33; c += 4) {
        int n0 = c * 256;
        int n = n0 + cl;
        bool ok = (n <= 8200);
        #pragma unroll
        for (int r0 = 0; r0 < 32; r0++) {
            int o = half * 32 + r0;
            float xv = ok ? vb[(size_t)o * SROW + n] : 0.f;
            u16 h, lo;
            bf16split(xv, h, lo);
            int raw = o * 128 + nl * 2;
            int swz = (o & 7) << 4;
            wr[(raw ^ swz) >> 1] = h;
            wr[((raw + 64) ^ swz) >> 1] = lo;
        }
        __syncthreads();
        int nstep = (n0 >> 5) + wv;
        if (nstep > NSTEPS - 1) nstep = NSTEPS - 1;   // masked-zero B anyway
        const u16* at = Tdft + (size_t)nstep * 2048;
        bf16x8 Th0 = *(const bf16x8*)(at + lane * 8);
        bf16x8 Tl0 = *(const bf16x8*)(at + 512 + lane * 8);
        bf16x8 Th1 = *(const bf16x8*)(at + 1024 + lane * 8);
        bf16x8 Tl1 = *(const bf16x8*)(at + 1536 + lane * 8);
        const u16* rd = outT + wv * 4096;
        #pragma unroll
        for (int ot = 0; ot < 4; ot++) {
            int o = ot * 16 + (lane & 15);
            int swz = (o & 7) << 4;
            bf16x8 Bh = *(const bf16x8*)(rd + (((o * 128 + g * 16) ^ swz) >> 1));
            bf16x8 Bl = *(const bf16x8*)(rd + (((o * 128 + 64 + g * 16) ^ swz) >> 1));
            dacc[0][ot] = __builtin_amdgcn_mfma_f32_16x16x32_bf16(Th0, Bh, dacc[0][ot], 0, 0, 0);
            dacc[0][ot] = __builtin_amdgcn_mfma_f32_16x16x32_bf16(Th0, Bl, dacc[0][ot], 0, 0, 0);
            dacc[0][ot] = __builtin_amdgcn_mfma_f32_16x16x32_bf16(Tl0, Bh, dacc[0][ot], 0, 0, 0);
            dacc[0][ot] = __builtin_amdgcn_mfma_f32_16x16x32_bf16(Tl0, Bl, dacc[0][ot], 0, 0, 0);
            dacc[1][ot] = __builtin_amdgcn_mfma_f32_16x16x32_bf16(Th1, Bh, dacc[1][ot], 0, 0, 0);
            dacc[1][ot] = __builtin_amdgcn_mfma_f32_16x16x32_bf16(Th1, Bl, dacc[1][ot], 0, 0, 0);
            dacc[1][ot] = __builtin_amdgcn_mfma_f32_16x16x32_bf16(Tl1, Bh, dacc[1][ot], 0, 0, 0);
            dacc[1][ot] = __builtin_amdgcn_mfma_f32_16x16x32_bf16(Tl1, Bl, dacc[1][ot], 0, 0, 0);
        }
        __syncthreads();
    }

    // reduce 8 wave-partials (reuse outT memory as f32 regions)
    float* rw = (float*)outT + wv * 2048;
    #pragma unroll
    for (int kt = 0; kt < 2; kt++)
        #pragma unroll
        for (int ot = 0; ot < 4; ot++) {
            int o = ot * 16 + (lane & 15);
            int kcb = kt * 16 + ((lane >> 4) << 2);
            rw[(kcb + 0) * 64 + o] = dacc[kt][ot][0];
            rw[(kcb + 1) * 64 + o] = dacc[kt][ot][1];
            rw[(kcb + 2) * 64 + o] = dacc[kt][ot][2];
            rw[(kcb + 3) * 64 + o] = dacc[kt][ot][3];
        }
    __syncthreads();
    {
        const float* rr = (const float*)outT;
        int idx = t * 4;
        float4 s = *(const float4*)(rr + idx);
        #pragma unroll
        for (int w2 = 1; w2 < 8; w2++) {
            float4 p = *(const float4*)(rr + w2 * 2048 + idx);
            s.x += p.x; s.y += p.y; s.z += p.z; s.w += p.w;
        }
        *(float4*)(Fpart + (size_t)b * fstride + (size_t)grp * 2048 + idx) = s;
    }
}

// Write one W-matrix value (row 64+kk, col o) into per-b ks2 A-frags (hi+lo).
__device__ __forceinline__ void wfrag(u16* wb2, int mt, int kk, int ol, float val) {
    int lane = ol + (((kk & 15) >> 2) << 4);
    int e = (kk & 3) + ((kk >> 4) << 2);
    u16 h, lo;
    bf16split(val, h, lo);
    wb2[(size_t)mt * 512 + lane * 8 + e] = h;
    wb2[(size_t)(4 + mt) * 512 + lane * 8 + e] = lo;
}

// Mode mix. Phase 1: reduce Fpart[b][0..nblk) into LDS Fs[8][64] (rows 0-3 =
// Re modes kg4..kg4+3, rows 4-7 = Im). Phase 2: P = F*kern, emit spectral
// A-frags WfA2[b].
__global__ __launch_bounds__(256) void kmix(const float* __restrict__ Fpart,
        const float* __restrict__ kr, const float* __restrict__ ki,
        const float* __restrict__ cb, u16* __restrict__ WfA2, int l,
        int nblk, int fstride) {
    int b = blockIdx.x, kg = blockIdx.y;
    int t = threadIdx.x;
    int o = t & 63, ii = t >> 6;
    __shared__ float Fs[8][64];
    {
        const float* fp = Fpart + (size_t)b * fstride;
        int r0 = t >> 6, oo = t & 63;
        int kc0 = kg * 4 + r0;          // cos rows (Re)
        int kc1 = 16 + kg * 4 + r0;     // sin rows (Im)
        float s0 = 0.f, s1 = 0.f, s2 = 0.f, s3 = 0.f;
        int blk = 0;
        for (; blk + 2 <= nblk; blk += 2) {
            s0 += fp[(size_t)blk * 2048 + kc0 * 64 + oo];
            s1 += fp[(size_t)(blk + 1) * 2048 + kc0 * 64 + oo];
            s2 += fp[(size_t)blk * 2048 + kc1 * 64 + oo];
            s3 += fp[(size_t)(blk + 1) * 2048 + kc1 * 64 + oo];
        }
        if (blk < nblk) {
            s0 += fp[(size_t)blk * 2048 + kc0 * 64 + oo];
            s2 += fp[(size_t)blk * 2048 + kc1 * 64 + oo];
        }
        Fs[r0][oo] = s0 + s1;
        Fs[4 + r0][oo] = s2 + s3;
    }
    __syncthreads();

    const float* krl = kr + (size_t)l * W * W * M;
    const float* kil = ki + (size_t)l * W * W * M;
    float pr[4] = {0.f, 0.f, 0.f, 0.f}, pi[4] = {0.f, 0.f, 0.f, 0.f};
    for (int i = ii * 16; i < ii * 16 + 16; i++) {
        float4 kr4 = *(const float4*)(krl + ((size_t)i * W + o) * M + kg * 4);
        float4 ki4 = *(const float4*)(kil + ((size_t)i * W + o) * M + kg * 4);
        float re0 = Fs[0][i], im0 = Fs[4][i];
        float re1 = Fs[1][i], im1 = Fs[5][i];
        float re2 = Fs[2][i], im2 = Fs[6][i];
        float re3 = Fs[3][i], im3 = Fs[7][i];
        pr[0] += re0 * kr4.x - im0 * ki4.x;  pi[0] += re0 * ki4.x + im0 * kr4.x;
        pr[1] += re1 * kr4.y - im1 * ki4.y;  pi[1] += re1 * ki4.y + im1 * kr4.y;
        pr[2] += re2 * kr4.z - im2 * ki4.z;  pi[2] += re2 * ki4.z + im2 * kr4.z;
        pr[3] += re3 * kr4.w - im3 * ki4.w;  pi[3] += re3 * ki4.w + im3 * kr4.w;
    }
    __shared__ float red[4][64][8];
    #pragma unroll
    for (int c = 0; c < 4; c++) {
        red[ii][o][2 * c]     = pr[c];
        red[ii][o][2 * c + 1] = pi[c];
    }
    __syncthreads();
    if (ii == 0) {
        u16* wb2 = WfA2 + (size_t)b * 4096;
        int mt = o >> 4, ol = o & 15;
        #pragma unroll
        for (int c = 0; c < 4; c++) {
            int k = kg * 4 + c;
            float sr = red[0][o][2 * c] + red[1][o][2 * c] + red[2][o][2 * c] + red[3][o][2 * c];
            float si = red[0][o][2 * c + 1] + red[1][o][2 * c + 1] + red[2][o][2 * c + 1] + red[3][o][2 * c + 1];
            if (k == 0) {
                wfrag(wb2, mt, 30, ol, cb[l * W + o] + sr * (1.0f / (float)NLEN));
                wfrag(wb2, mt, 31, ol, 0.0f);
            } else {
                wfrag(wb2, mt, k - 1,  ol, sr * (2.0f / (float)NLEN));
                wfrag(wb2, mt, 14 + k, ol, -si * (2.0f / (float)NLEN));
            }
        }
    }
}

// Fused conv + inverse transform + gelu via bf16-split MFMA, IN-PLACE, plus
// (dodft) fused forward-DFT of the OUTPUT: each wave re-packs its gelu'd
// 64o x 32n tile into swizzled bf16 LDS B-frags (reusing fragU), contracts
// against Tdft A-frags, reduces across 8 waves, writes Fpart[b][blockIdx.x].
__global__ __launch_bounds__(512, 4) void kconv(float* __restrict__ v,
        const u16* __restrict__ AcwL, const u16* __restrict__ WfA2,
        const u16* __restrict__ Ustat, const u16* __restrict__ Tdft,
        float* __restrict__ Fpart, int fstride, int dodft) {
    __shared__ __align__(16) u16 fragU[2][2][16][64][8];   // 64 KB
    int t = threadIdx.x;
    int b = blockIdx.y;
    int n0 = blockIdx.x * 256;
    int lane = t & 63;
    int wv = __builtin_amdgcn_readfirstlane(t >> 6);       // 0..7
    float* vb = v + (size_t)b * W * SROW;

    // ---- load 64 v-rows x 256 cols, split to bf16 hi/lo frags in LDS ----
    {
        int col = t & 255;
        int half = t >> 8;                 // 0/1
        int nt = col >> 4;
        int lt = col & 15;
        #pragma unroll
        for (int q = 0; q < 8; q++) {
            int quad = q * 2 + half;       // 0..15 -> rows 4q..4q+3
            const float* src = vb + (size_t)(quad * 4) * SROW + n0 + col;
            float x0 = src[0];
            float x1 = src[SROW];
            float x2 = src[2 * SROW];
            float x3 = src[3 * SROW];
            int ks = quad >> 3;
            int laneT = lt + ((quad & 3) << 4);
            int e0 = ((quad >> 2) & 1) << 2;
            u16 h0, l0, h1, l1, h2, l2, h3, l3;
            bf16split(x0, h0, l0); bf16split(x1, h1, l1);
            bf16split(x2, h2, l2); bf16split(x3, h3, l3);
            short4v hv = {(short)h0, (short)h1, (short)h2, (short)h3};
            short4v lv = {(short)l0, (short)l1, (short)l2, (short)l3};
            *(short4v*)&fragU[ks][0][nt][laneT][e0] = hv;
            *(short4v*)&fragU[ks][1][nt][laneT][e0] = lv;
        }
    }

    f32x4 acc[4][2];
    #pragma unroll
    for (int mt = 0; mt < 4; mt++)
        #pragma unroll
        for (int j = 0; j < 2; j++)
            acc[mt][j] = (f32x4){0.f, 0.f, 0.f, 0.f};

    __syncthreads();

    const u16* wb2 = WfA2 + (size_t)b * 4096;
    int nt0 = wv * 2;
    #pragma unroll
    for (int ks = 0; ks < 3; ks++) {
        const u16* ab = (ks < 2) ? (AcwL + (size_t)ks * 4096) : wb2;
        bf16x8 Ah[4], Al[4];
        #pragma unroll
        for (int mt = 0; mt < 4; mt++) {
            Ah[mt] = *(const bf16x8*)(ab + (size_t)mt * 512 + lane * 8);
            Al[mt] = *(const bf16x8*)(ab + (size_t)(4 + mt) * 512 + lane * 8);
        }
        #pragma unroll
        for (int ntl = 0; ntl < 2; ntl++) {
            bf16x8 Bh, Bl;
            if (ks < 2) {
                Bh = *(const bf16x8*)&fragU[ks][0][nt0 + ntl][lane][0];
                Bl = *(const bf16x8*)&fragU[ks][1][nt0 + ntl][lane][0];
            } else {
                int ntg = (n0 >> 4) + nt0 + ntl;
                if (ntg >= NT_STAT) ntg = NT_STAT - 1;   // OOB cols: finite junk
                Bh = *(const bf16x8*)(Ustat + ((size_t)ntg * 64 + lane) * 8);
                Bl = *(const bf16x8*)(Ustat + (size_t)NT_STAT * 512 + ((size_t)ntg * 64 + lane) * 8);
            }
            #pragma unroll
            for (int mt = 0; mt < 4; mt++) {
                acc[mt][ntl] = __builtin_amdgcn_mfma_f32_16x16x32_bf16(Ah[mt], Bh, acc[mt][ntl], 0, 0, 0);
                acc[mt][ntl] = __builtin_amdgcn_mfma_f32_16x16x32_bf16(Ah[mt], Bl, acc[mt][ntl], 0, 0, 0);
                acc[mt][ntl] = __builtin_amdgcn_mfma_f32_16x16x32_bf16(Al[mt], Bh, acc[mt][ntl], 0, 0, 0);
                acc[mt][ntl] = __builtin_amdgcn_mfma_f32_16x16x32_bf16(Al[mt], Bl, acc[mt][ntl], 0, 0, 0);
            }
        }
    }

    // ---- epilogue: gelu (in-place on acc) + store ----
    int r4 = (lane >> 4) << 2;
    #pragma unroll
    for (int ntl = 0; ntl < 2; ntl++) {
        int n = n0 + wv * 32 + ntl * 16 + (lane & 15);
        #pragma unroll
        for (int mt = 0; mt < 4; mt++) {
            acc[mt][ntl][0] = gelu_f(acc[mt][ntl][0]);
            acc[mt][ntl][1] = gelu_f(acc[mt][ntl][1]);
            acc[mt][ntl][2] = gelu_f(acc[mt][ntl][2]);
            acc[mt][ntl][3] = gelu_f(acc[mt][ntl][3]);
        }
        if (n < SROW) {
            #pragma unroll
            for (int mt = 0; mt < 4; mt++) {
                float* vo = vb + (size_t)(mt * 16 + r4) * SROW + n;
                vo[0]        = acc[mt][ntl][0];
                vo[SROW]     = acc[mt][ntl][1];
                vo[2 * SROW] = acc[mt][ntl][2];
                vo[3 * SROW] = acc[mt][ntl][3];
            }
        }
    }

    // ---- fused forward-DFT of the output tile ----
    if (dodft) {
        __syncthreads();                       // all waves done reading fragU
        u16* outW = ((u16*)fragU) + wv * 4096; // per-wave region, self-only
        int nbase = n0 + wv * 32;
        #pragma unroll
        for (int ntl = 0; ntl < 2; ntl++) {
            int nl = ntl * 16 + (lane & 15);
            bool ok = (nbase + nl) <= 8200;    // DFT covers n in [0,8200]
            #pragma unroll
            for (int mt = 0; mt < 4; mt++) {
                #pragma unroll
                for (int j = 0; j < 4; j++) {
                    int oo = mt * 16 + r4 + j;
                    float gv = ok ? acc[mt][ntl][j] : 0.f;
                    u16 h, lo;
                    bf16split(gv, h, lo);
                    int raw = oo * 128 + nl * 2;
                    int swz = (oo & 7) << 4;
                    outW[(raw ^ swz) >> 1] = h;
                    outW[((raw + 64) ^ swz) >> 1] = lo;
                }
            }
        }
        int nstep = (n0 >> 5) + wv;
        if (nstep > NSTEPS - 1) nstep = NSTEPS - 1;
        const u16* at = Tdft + (size_t)nstep * 2048;
        bf16x8 Th0 = *(const bf16x8*)(at + lane * 8);
        bf16x8 Tl0 = *(const bf16x8*)(at + 512 + lane * 8);
        bf16x8 Th1 = *(const bf16x8*)(at + 1024 + lane * 8);
        bf16x8 Tl1 = *(const bf16x8*)(at + 1536 + lane * 8);
        f32x4 dacc[2][4];
        #pragma unroll
        for (int kt = 0; kt < 2; kt++)
            #pragma unroll
            for (int ot = 0; ot < 4; ot++) dacc[kt][ot] = (f32x4){0.f, 0.f, 0.f, 0.f};
        int g = lane >> 4;
        #pragma unroll
        for (int ot = 0; ot < 4; ot++) {
            int oo = ot * 16 + (lane & 15);
            int swz = (oo & 7) << 4;
            bf16x8 Bh = *(const bf16x8*)(outW + (((oo * 128 + g * 16) ^ swz) >> 1));
            bf16x8 Bl = *(const bf16x8*)(outW + (((oo * 128 + 64 + g * 16) ^ swz) >> 1));
            dacc[0][ot] = __builtin_amdgcn_mfma_f32_16x16x32_bf16(Th0, Bh, dacc[0][ot], 0, 0, 0);
            dacc[0][ot] = __builtin_amdgcn_mfma_f32_16x16x32_bf16(Th0, Bl, dacc[0][ot], 0, 0, 0);
            dacc[0][ot] = __builtin_amdgcn_mfma_f32_16x16x32_bf16(Tl0, Bh, dacc[0][ot], 0, 0, 0);
            dacc[0][ot] = __builtin_amdgcn_mfma_f32_16x16x32_bf16(Tl0, Bl, dacc[0][ot], 0, 0, 0);
            dacc[1][ot] = __builtin_amdgcn_mfma_f32_16x16x32_bf16(Th1, Bh, dacc[1][ot], 0, 0, 0);
            dacc[1][ot] = __builtin_amdgcn_mfma_f32_16x16x32_bf16(Th1, Bl, dacc[1][ot], 0, 0, 0);
            dacc[1][ot] = __builtin_amdgcn_mfma_f32_16x16x32_bf16(Tl1, Bh, dacc[1][ot], 0, 0, 0);
            dacc[1][ot] = __builtin_amdgcn_mfma_f32_16x16x32_bf16(Tl1, Bl, dacc[1][ot], 0, 0, 0);
        }
        // cross-wave reduce (own region overwrite, then barrier, then sum)
        float* rw = (float*)fragU + wv * 2048;
        #pragma unroll
        for (int kt = 0; kt < 2; kt++)
            #pragma unroll
            for (int ot = 0; ot < 4; ot++) {
                int oo = ot * 16 + (lane & 15);
                int kcb = kt * 16 + ((lane >> 4) << 2);
                rw[(kcb + 0) * 64 + oo] = dacc[kt][ot][0];
                rw[(kcb + 1) * 64 + oo] = dacc[kt][ot][1];
                rw[(kcb + 2) * 64 + oo] = dacc[kt][ot][2];
                rw[(kcb + 3) * 64 + oo] = dacc[kt][ot][3];
            }
        __syncthreads();
        {
            const float* rr = (const float*)fragU;
            int idx = t * 4;
            float4 s = *(const float4*)(rr + idx);
            #pragma unroll
            for (int w2 = 1; w2 < 8; w2++) {
                float4 p = *(const float4*)(rr + w2 * 2048 + idx);
                s.x += p.x; s.y += p.y; s.z += p.z; s.w += p.w;
            }
            *(float4*)(Fpart + (size_t)b * fstride + (size_t)blockIdx.x * 2048 + idx) = s;
        }
    }
}

// Final projection: 1024 threads = 16 waves; wave w owns h rows [8w,8w+8).
__global__ __launch_bounds__(1024, 8) void kproj(const float* __restrict__ v,
        const float* __restrict__ w1, const float* __restrict__ b1,
        const float* __restrict__ w2, const float* __restrict__ b2,
        float* __restrict__ out) {
    __shared__ __align__(16) float U[2][8][256];
    __shared__ __align__(16) float red[16][256];
    int t = threadIdx.x;
    int b = blockIdx.y;
    int n0 = blockIdx.x * 256;
    int lane = t & 63;
    int wvu = __builtin_amdgcn_readfirstlane(t >> 6);
    const float* vb = v + (size_t)b * (W * SROW);
    int colf = n0 + lane * 4;
    int h0 = wvu * 8;

    if (wvu < 8) gld16(vb + (size_t)wvu * SROW + colf, &U[0][wvu][0]);

    float acc[8][4];
    #pragma unroll
    for (int r = 0; r < 8; r++) {
        float bs = b1[h0 + r];
        acc[r][0] = acc[r][1] = acc[r][2] = acc[r][3] = bs;
    }
    __syncthreads();

    int buf = 0;
    for (int c = 0; c < 8; c++) {
        if (c < 7 && wvu < 8)
            gld16(vb + (size_t)((c + 1) * 8 + wvu) * SROW + colf, &U[buf ^ 1][wvu][0]);
        #pragma unroll
        for (int kk = 0; kk < 8; kk++) {
            int k = c * 8 + kk;
            float4 u = *(const float4*)&U[buf][kk][lane * 4];
            const float* wk = w1 + k * 128 + h0;
            #pragma unroll
            for (int r = 0; r < 8; r++) {
                float wr = wk[r];
                acc[r][0] = fmaf(wr, u.x, acc[r][0]);
                acc[r][1] = fmaf(wr, u.y, acc[r][1]);
                acc[r][2] = fmaf(wr, u.z, acc[r][2]);
                acc[r][3] = fmaf(wr, u.w, acc[r][3]);
            }
        }
        if (c < 7) { __syncthreads(); buf ^= 1; }
    }

    float p0 = 0.f, p1 = 0.f, p2 = 0.f, p3 = 0.f;
    #pragma unroll
    for (int r = 0; r < 8; r++) {
        float wh = w2[h0 + r];
        p0 = fmaf(gelu_f(acc[r][0]), wh, p0);
        p1 = fmaf(gelu_f(acc[r][1]), wh, p1);
        p2 = fmaf(gelu_f(acc[r][2]), wh, p2);
        p3 = fmaf(gelu_f(acc[r][3]), wh, p3);
    }
    float4 p4 = {p0, p1, p2, p3};
    *(float4*)&red[wvu][lane * 4] = p4;
    __syncthreads();
    if (t < 256) {
        float s = b2[0];
        #pragma unroll
        for (int w = 0; w < 16; w++) s += red[w][t];
        out[(size_t)b * 8192 + n0 + t] = s;
    }
}

extern "C" void kernel_launch(void* const* d_in, const int* in_sizes, int n_in,
                              void* d_out, int out_size, void* d_ws, size_t ws_size,
                              hipStream_t stream) {
    const float* x  = (const float*)d_in[0];
    const float* lw = (const float*)d_in[1];
    const float* lb = (const float*)d_in[2];
    const float* kr = (const float*)d_in[3];
    const float* ki = (const float*)d_in[4];
    const float* cw = (const float*)d_in[5];
    const float* cb = (const float*)d_in[6];
    const float* w1 = (const float*)d_in[7];
    const float* b1 = (const float*)d_in[8];
    const float* w2 = (const float*)d_in[9];
    const float* b2 = (const float*)d_in[10];
    float* out = (float*)d_out;

    // workspace: v (134.7MB f32) | u16 planes: Ustat 1.05MB, Acw 80KB,
    // WfA2 512KB, Tdft 1.05MB | Fpart f32 (fused: 17.3MB -> ~155MB total;
    // legacy: 2.1MB -> ~140MB total)
    float* ws = (float*)d_ws;
    size_t vsz = (size_t)NB * W * SROW;
    float* v    = ws;
    u16* Ustat  = (u16*)(v + vsz);
    u16* AcwBuf = Ustat + (size_t)2 * NT_STAT * 512;
    u16* WfA2   = AcwBuf + (size_t)NL * 8192;
    u16* Tdft   = WfA2 + (size_t)NB * 4096;
    size_t u16_total = (size_t)2 * NT_STAT * 512 + (size_t)NL * 8192
                     + (size_t)NB * 4096 + (size_t)NSTEPS * 2048;
    size_t fpart_off = vsz + u16_total / 2;          // u16_total is even
    float* Fpart = ws + fpart_off;
    size_t need_fused = (fpart_off + (size_t)NB * 33 * 2048) * sizeof(float);
    int fused = (ws_size >= need_fused) ? 1 : 0;
    int fstride = fused ? (33 * 2048) : (4 * 2048);

    kstat<<<dim3(NT_STAT), 256, 0, stream>>>(Ustat);
    kdtab<<<dim3(NSTEPS), 256, 0, stream>>>(Tdft);
    kprep<<<dim3(NL), 256, 0, stream>>>(cw, AcwBuf);
    klift<<<dim3(9, NB), 256, 0, stream>>>(x, lw, lb, v);

    if (fused) {
        kdft2<<<dim3(NB, 4), 512, 0, stream>>>(v, Tdft, Fpart, fstride);
        for (int l = 0; l < NL; l++) {
            kmix<<<dim3(NB, 4), 256, 0, stream>>>(Fpart, kr, ki, cb, WfA2, l,
                                                  (l == 0) ? 4 : 33, fstride);
            kconv<<<dim3(33, NB), 512, 0, stream>>>(v, AcwBuf + (size_t)l * 8192,
                    WfA2, Ustat, Tdft, Fpart, fstride, (l < NL - 1) ? 1 : 0);
        }
    } else {
        for (int l = 0; l < NL; l++) {
            kdft2<<<dim3(NB, 4), 512, 0, stream>>>(v, Tdft, Fpart, fstride);
            kmix<<<dim3(NB, 4), 256, 0, stream>>>(Fpart, kr, ki, cb, WfA2, l,
                                                  4, fstride);
            kconv<<<dim3(33, NB), 512, 0, stream>>>(v, AcwBuf + (size_t)l * 8192,
                    WfA2, Ustat, Tdft, Fpart, fstride, 0);
        }
    }
    kproj<<<dim3(32, NB), 1024, 0, stream>>>(v, w1, b1, w2, b2, out);
}

// Round 3
// 643.010 us; speedup vs baseline: 1.5991x; 1.1958x over previous
//
#include <hip/hip_runtime.h>
#include <math.h>

// FNO1d: B=64, N=8192, F_IN=2, W=64, L=5, M=16, PAD=9 -> NLEN=8201
#define SROW 8224      // row stride: 8224*4 = 32896 B, 128B-aligned rows
#define NLEN 8201
#define NB 64
#define W 64
#define M 16
#define NL 5
#define TWO_PI 6.283185307179586476925286766559
#define NT_STAT 514    // static B-frag n-tiles (n < 8224); OOB tiles clamp here
#define NSTEPS 257     // DFT twiddle A-frag K-steps of 32 (covers n < 8224)

typedef unsigned short u16;
typedef __attribute__((ext_vector_type(8))) short bf16x8;   // MFMA A/B frag (4 VGPR)
typedef __attribute__((ext_vector_type(4))) float f32x4;    // MFMA C/D frag
typedef __attribute__((ext_vector_type(4))) short short4v;

// ---- bf16 split-precision helpers (x = hi + lo, both RN bf16) ----
__device__ __forceinline__ u16 bf16rn(float x) {
    unsigned u = __float_as_uint(x);
    unsigned r = (u + 0x7fffu + ((u >> 16) & 1u)) >> 16;
    return (u16)r;
}
__device__ __forceinline__ float bf16tof(u16 h) {
    return __uint_as_float(((unsigned)h) << 16);
}
__device__ __forceinline__ void bf16split(float x, u16& h, u16& lo) {
    h = bf16rn(x);
    lo = bf16rn(x - bf16tof(h));
}

// Both MFMA operand sides always use the SAME (lane>>4, e) -> kk bijection, so
// the hardware's exact within-K ordering cancels out of every contraction.
//   main GEMM:     kk(g,e) = g*4 + (e&3) + 16*(e>>2)
//   DFT epilogue:  nloc(g,e) = g*8 + e

// Branchless gelu: A&S 7.1.26 erf (|err| <= 1.5e-7), rcp+exp fast paths.
__device__ __forceinline__ float gelu_f(float x) {
    float s = x * 0.70710678118654752f;
    float a = fabsf(s);
    float t = __builtin_amdgcn_rcpf(fmaf(0.3275911f, a, 1.0f));
    float p = fmaf(1.061405429f, t, -1.453152027f);
    p = fmaf(p, t, 1.421413741f);
    p = fmaf(p, t, -0.284496736f);
    p = fmaf(p, t, 0.254829592f);
    p = p * t;
    float e = __expf(-a * a);
    float er = copysignf(fmaf(-p, e, 1.0f), s);
    float h = 0.5f * x;
    return fmaf(h, er, h);
}

// Static B-frags for main-GEMM ks=2 (U rows 64..95 = [cos1..15|sin1..15|1|0]).
__global__ __launch_bounds__(256) void kstat(u16* __restrict__ Ustat) {
    int nt = blockIdx.x;             // 0..NT_STAT-1
    int t = threadIdx.x;
    for (int s = t; s < 512; s += 256) {
        int lane = s >> 3, e = s & 7;
        int kk = ((lane >> 4) << 2) + (e & 3) + ((e >> 2) << 4);
        int r = 64 + kk;
        int n = nt * 16 + (lane & 15);
        float val;
        if (r < 94) {
            int k = (r < 79) ? (r - 63) : (r - 78);
            long long mm = ((long long)k * (long long)n) % NLEN;
            double th = (TWO_PI / (double)NLEN) * (double)mm;
            double sv, cv;
            sincos(th, &sv, &cv);
            val = (float)((r < 79) ? cv : sv);
        } else {
            val = (r == 94) ? 1.0f : 0.0f;
        }
        u16 h, lo;
        bf16split(val, h, lo);
        size_t base = ((size_t)nt * 64 + lane) * 8 + e;
        Ustat[base] = h;
        Ustat[(size_t)NT_STAT * 512 + base] = lo;
    }
}

// Twiddle A-frags for the fused DFT: Tdft[nstep][kcT(2)][hl(2)][lane][e].
// A[m=kc][n]: kc<16 -> cos(2pi*kc*n/NLEN); kc>=16 -> -sin(2pi*(kc-16)*n/NLEN).
__global__ __launch_bounds__(256) void kdtab(u16* __restrict__ Tdft) {
    int nstep = blockIdx.x;
    int t = threadIdx.x;
    for (int s = t; s < 1024; s += 256) {     // kcT(2) x lane(64) x e(8)
        int e = s & 7, lane = (s >> 3) & 63, kcT = s >> 9;
        int kc = kcT * 16 + (lane & 15);
        int n = nstep * 32 + ((lane >> 4) << 3) + e;
        int k = kc & 15;
        long long m = ((long long)k * (long long)n) % NLEN;
        double th = (TWO_PI / (double)NLEN) * (double)m;
        double sv, cv;
        sincos(th, &sv, &cv);
        float val = (kc < 16) ? (float)cv : (float)(-sv);
        u16 h, lo;
        bf16split(val, h, lo);
        size_t base = (((size_t)nstep * 2 + kcT) * 2) * 512 + lane * 8 + e;
        Tdft[base] = h;
        Tdft[base + 512] = lo;
    }
}

// Pack cw (all 5 layers) into A-frags: AcwBuf[l][ks(2)][hl(2)][mt(4)][lane][e].
__global__ __launch_bounds__(256) void kprep(const float* __restrict__ cw,
                                             u16* __restrict__ AcwBuf) {
    int l = blockIdx.x;
    int t = threadIdx.x;
    const float* cwl = cw + (size_t)l * W * W;
    u16* ob = AcwBuf + (size_t)l * 8192;
    for (int s = t; s < 4096; s += 256) {
        int e = s & 7, lane = (s >> 3) & 63, mt = (s >> 9) & 3, ks = s >> 11;
        int kk = ((lane >> 4) << 2) + (e & 3) + ((e >> 2) << 4);
        int k = ks * 32 + kk;
        int o = mt * 16 + (lane & 15);
        u16 h, lo;
        bf16split(cwl[o * 64 + k], h, lo);
        ob[(((size_t)ks * 2 + 0) * 4 + mt) * 512 + lane * 8 + e] = h;
        ob[(((size_t)ks * 2 + 1) * 4 + mt) * 512 + lane * 8 + e] = lo;
    }
}

// Pack w1 (64k x 128h) into A-frags: Aw1[ks(2)][hl(2)][mt(8)][lane][e].
// A[m=h][k] = w1[k*128+h].
__global__ __launch_bounds__(256) void kprep2(const float* __restrict__ w1,
                                              u16* __restrict__ Aw1) {
    int t = threadIdx.x;
    for (int s = t; s < 8192; s += 256) {    // ks(2) x mt(8) x lane(64) x e(8)
        int e = s & 7, lane = (s >> 3) & 63, mt = (s >> 9) & 7, ks = s >> 12;
        int kk = ((lane >> 4) << 2) + (e & 3) + ((e >> 2) << 4);
        int k = ks * 32 + kk;
        int h = mt * 16 + (lane & 15);
        u16 hh, lo;
        bf16split(w1[k * 128 + h], hh, lo);
        Aw1[(((size_t)ks * 2 + 0) * 8 + mt) * 512 + lane * 8 + e] = hh;
        Aw1[(((size_t)ks * 2 + 1) * 8 + mt) * 512 + lane * 8 + e] = lo;
    }
}

// Legacy lift (fallback path only).
__global__ __launch_bounds__(256) void klift(const float* __restrict__ x,
        const float* __restrict__ lw, const float* __restrict__ lb,
        float* __restrict__ v) {
    int n4 = blockIdx.x * 256 + threadIdx.x;
    int b = blockIdx.y;
    if (n4 >= 2056) return;
    int n = n4 * 4;
    bool in = (n < 8192);
    float4 xa = {0.f, 0.f, 0.f, 0.f}, xb = {0.f, 0.f, 0.f, 0.f};
    if (in) {
        const float* xp = x + ((size_t)b * 8192 + n) * 2;
        xa = *(const float4*)xp;
        xb = *(const float4*)(xp + 4);
    }
    float* vp = v + (size_t)b * W * SROW + n;
    #pragma unroll
    for (int w = 0; w < W; w++) {
        float4 o4 = {0.f, 0.f, 0.f, 0.f};
        if (in) {
            float l0 = lw[w], l1 = lw[W + w], bb = lb[w];
            o4.x = fmaf(xa.x, l0, fmaf(xa.y, l1, bb));
            o4.y = fmaf(xa.z, l0, fmaf(xa.w, l1, bb));
            o4.z = fmaf(xb.x, l0, fmaf(xb.y, l1, bb));
            o4.w = fmaf(xb.z, l0, fmaf(xb.w, l1, bb));
        }
        *(float4*)(vp + (size_t)w * SROW) = o4;
    }
}

// Fused lift + forward-DFT (fused path): block = 64w x 256n tile. Lift is
// computed directly in the kconv acc layout (o = mt*16 + r4 + j,
// n = n0 + wv*32 + ntl*16 + lane&15), stored to v, then the standard DFT
// epilogue (pack bf16 frags -> Tdft MFMAs -> cross-wave reduce -> Fpart).
__global__ __launch_bounds__(512, 4) void klift2(const float* __restrict__ x,
        const float* __restrict__ lw, const float* __restrict__ lb,
        float* __restrict__ v, const u16* __restrict__ Tdft,
        float* __restrict__ Fpart, int fstride) {
    __shared__ __align__(16) u16 outT[8 * 4096];   // 64 KB
    int t = threadIdx.x;
    int b = blockIdx.y;
    int n0 = blockIdx.x * 256;
    int lane = t & 63;
    int wv = __builtin_amdgcn_readfirstlane(t >> 6);
    float* vb = v + (size_t)b * W * SROW;
    int r4 = (lane >> 4) << 2;

    f32x4 acc[4][2];
    #pragma unroll
    for (int ntl = 0; ntl < 2; ntl++) {
        int n = n0 + wv * 32 + ntl * 16 + (lane & 15);
        float x0 = 0.f, x1 = 0.f;
        bool in = (n < 8192);
        if (in) {
            const float* xp = x + ((size_t)b * 8192 + n) * 2;
            x0 = xp[0]; x1 = xp[1];
        }
        #pragma unroll
        for (int mt = 0; mt < 4; mt++) {
            #pragma unroll
            for (int j = 0; j < 4; j++) {
                int o = mt * 16 + r4 + j;
                acc[mt][ntl][j] = in ? fmaf(x0, lw[o], fmaf(x1, lw[64 + o], lb[o])) : 0.f;
            }
        }
        if (n < SROW) {
            #pragma unroll
            for (int mt = 0; mt < 4; mt++) {
                float* vo = vb + (size_t)(mt * 16 + r4) * SROW + n;
                vo[0]        = acc[mt][ntl][0];
                vo[SROW]     = acc[mt][ntl][1];
                vo[2 * SROW] = acc[mt][ntl][2];
                vo[3 * SROW] = acc[mt][ntl][3];
            }
        }
    }

    // ---- DFT epilogue (same scheme as kconv dodft) ----
    u16* outW = outT + wv * 4096;
    #pragma unroll
    for (int ntl = 0; ntl < 2; ntl++) {
        int nl = ntl * 16 + (lane & 15);
        #pragma unroll
        for (int mt = 0; mt < 4; mt++) {
            #pragma unroll
            for (int j = 0; j < 4; j++) {
                int oo = mt * 16 + r4 + j;
                u16 h, lo;
                bf16split(acc[mt][ntl][j], h, lo);   // pad cols are exact 0
                int raw = oo * 128 + nl * 2;
                int swz = (oo & 7) << 4;
                outW[(raw ^ swz) >> 1] = h;
                outW[((raw + 64) ^ swz) >> 1] = lo;
            }
        }
    }
    int nstep = (n0 >> 5) + wv;
    if (nstep > NSTEPS - 1) nstep = NSTEPS - 1;
    const u16* at = Tdft + (size_t)nstep * 2048;
    bf16x8 Th0 = *(const bf16x8*)(at + lane * 8);
    bf16x8 Tl0 = *(const bf16x8*)(at + 512 + lane * 8);
    bf16x8 Th1 = *(const bf16x8*)(at + 1024 + lane * 8);
    bf16x8 Tl1 = *(const bf16x8*)(at + 1536 + lane * 8);
    f32x4 dacc[2][4];
    #pragma unroll
    for (int kt = 0; kt < 2; kt++)
        #pragma unroll
        for (int ot = 0; ot < 4; ot++) dacc[kt][ot] = (f32x4){0.f, 0.f, 0.f, 0.f};
    int g = lane >> 4;
    #pragma unroll
    for (int ot = 0; ot < 4; ot++) {
        int oo = ot * 16 + (lane & 15);
        int swz = (oo & 7) << 4;
        bf16x8 Bh = *(const bf16x8*)(outW + (((oo * 128 + g * 16) ^ swz) >> 1));
        bf16x8 Bl = *(const bf16x8*)(outW + (((oo * 128 + 64 + g * 16) ^ swz) >> 1));
        dacc[0][ot] = __builtin_amdgcn_mfma_f32_16x16x32_bf16(Th0, Bh, dacc[0][ot], 0, 0, 0);
        dacc[0][ot] = __builtin_amdgcn_mfma_f32_16x16x32_bf16(Th0, Bl, dacc[0][ot], 0, 0, 0);
        dacc[0][ot] = __builtin_amdgcn_mfma_f32_16x16x32_bf16(Tl0, Bh, dacc[0][ot], 0, 0, 0);
        dacc[0][ot] = __builtin_amdgcn_mfma_f32_16x16x32_bf16(Tl0, Bl, dacc[0][ot], 0, 0, 0);
        dacc[1][ot] = __builtin_amdgcn_mfma_f32_16x16x32_bf16(Th1, Bh, dacc[1][ot], 0, 0, 0);
        dacc[1][ot] = __builtin_amdgcn_mfma_f32_16x16x32_bf16(Th1, Bl, dacc[1][ot], 0, 0, 0);
        dacc[1][ot] = __builtin_amdgcn_mfma_f32_16x16x32_bf16(Tl1, Bh, dacc[1][ot], 0, 0, 0);
        dacc[1][ot] = __builtin_amdgcn_mfma_f32_16x16x32_bf16(Tl1, Bl, dacc[1][ot], 0, 0, 0);
    }
    float* rw = (float*)outT + wv * 2048;
    #pragma unroll
    for (int kt = 0; kt < 2; kt++)
        #pragma unroll
        for (int ot = 0; ot < 4; ot++) {
            int oo = ot * 16 + (lane & 15);
            int kcb = kt * 16 + ((lane >> 4) << 2);
            rw[(kcb + 0) * 64 + oo] = dacc[kt][ot][0];
            rw[(kcb + 1) * 64 + oo] = dacc[kt][ot][1];
            rw[(kcb + 2) * 64 + oo] = dacc[kt][ot][2];
            rw[(kcb + 3) * 64 + oo] = dacc[kt][ot][3];
        }
    __syncthreads();
    {
        const float* rr = (const float*)outT;
        int idx = t * 4;
        float4 s = *(const float4*)(rr + idx);
        #pragma unroll
        for (int w2 = 1; w2 < 8; w2++) {
            float4 p = *(const float4*)(rr + w2 * 2048 + idx);
            s.x += p.x; s.y += p.y; s.z += p.z; s.w += p.w;
        }
        *(float4*)(Fpart + (size_t)b * fstride + (size_t)blockIdx.x * 2048 + idx) = s;
    }
}

// Standalone MFMA DFT (fallback path only).
__global__ __launch_bounds__(512, 4) void kdft2(const float* __restrict__ v,
        const u16* __restrict__ Tdft, float* __restrict__ Fpart, int fstride) {
    __shared__ __align__(16) u16 outT[8 * 4096];   // 64 KB: 8 wave-regions
    int t = threadIdx.x;
    int b = blockIdx.x, grp = blockIdx.y;
    int lane = t & 63;
    int wv = __builtin_amdgcn_readfirstlane(t >> 6);
    const float* vb = v + (size_t)b * W * SROW;

    f32x4 dacc[2][4];
    #pragma unroll
    for (int kt = 0; kt < 2; kt++)
        #pragma unroll
        for (int ot = 0; ot < 4; ot++) dacc[kt][ot] = (f32x4){0.f, 0.f, 0.f, 0.f};

    int cl = t & 255, half = t >> 8;
    int wvD = cl >> 5, nl = cl & 31;
    u16* wr = outT + wvD * 4096;
    int g = lane >> 4;

    for (int c = grp; c < 33; c += 4) {
        int n0 = c * 256;
        int n = n0 + cl;
        bool ok = (n <= 8200);
        #pragma unroll
        for (int r0 = 0; r0 < 32; r0++) {
            int o = half * 32 + r0;
            float xv = ok ? vb[(size_t)o * SROW + n] : 0.f;
            u16 h, lo;
            bf16split(xv, h, lo);
            int raw = o * 128 + nl * 2;
            int swz = (o & 7) << 4;
            wr[(raw ^ swz) >> 1] = h;
            wr[((raw + 64) ^ swz) >> 1] = lo;
        }
        __syncthreads();
        int nstep = (n0 >> 5) + wv;
        if (nstep > NSTEPS - 1) nstep = NSTEPS - 1;
        const u16* at = Tdft + (size_t)nstep * 2048;
        bf16x8 Th0 = *(const bf16x8*)(at + lane * 8);
        bf16x8 Tl0 = *(const bf16x8*)(at + 512 + lane * 8);
        bf16x8 Th1 = *(const bf16x8*)(at + 1024 + lane * 8);
        bf16x8 Tl1 = *(const bf16x8*)(at + 1536 + lane * 8);
        const u16* rd = outT + wv * 4096;
        #pragma unroll
        for (int ot = 0; ot < 4; ot++) {
            int o = ot * 16 + (lane & 15);
            int swz = (o & 7) << 4;
            bf16x8 Bh = *(const bf16x8*)(rd + (((o * 128 + g * 16) ^ swz) >> 1));
            bf16x8 Bl = *(const bf16x8*)(rd + (((o * 128 + 64 + g * 16) ^ swz) >> 1));
            dacc[0][ot] = __builtin_amdgcn_mfma_f32_16x16x32_bf16(Th0, Bh, dacc[0][ot], 0, 0, 0);
            dacc[0][ot] = __builtin_amdgcn_mfma_f32_16x16x32_bf16(Th0, Bl, dacc[0][ot], 0, 0, 0);
            dacc[0][ot] = __builtin_amdgcn_mfma_f32_16x16x32_bf16(Tl0, Bh, dacc[0][ot], 0, 0, 0);
            dacc[0][ot] = __builtin_amdgcn_mfma_f32_16x16x32_bf16(Tl0, Bl, dacc[0][ot], 0, 0, 0);
            dacc[1][ot] = __builtin_amdgcn_mfma_f32_16x16x32_bf16(Th1, Bh, dacc[1][ot], 0, 0, 0);
            dacc[1][ot] = __builtin_amdgcn_mfma_f32_16x16x32_bf16(Th1, Bl, dacc[1][ot], 0, 0, 0);
            dacc[1][ot] = __builtin_amdgcn_mfma_f32_16x16x32_bf16(Tl1, Bh, dacc[1][ot], 0, 0, 0);
            dacc[1][ot] = __builtin_amdgcn_mfma_f32_16x16x32_bf16(Tl1, Bl, dacc[1][ot], 0, 0, 0);
        }
        __syncthreads();
    }

    float* rw = (float*)outT + wv * 2048;
    #pragma unroll
    for (int kt = 0; kt < 2; kt++)
        #pragma unroll
        for (int ot = 0; ot < 4; ot++) {
            int o = ot * 16 + (lane & 15);
            int kcb = kt * 16 + ((lane >> 4) << 2);
            rw[(kcb + 0) * 64 + o] = dacc[kt][ot][0];
            rw[(kcb + 1) * 64 + o] = dacc[kt][ot][1];
            rw[(kcb + 2) * 64 + o] = dacc[kt][ot][2];
            rw[(kcb + 3) * 64 + o] = dacc[kt][ot][3];
        }
    __syncthreads();
    {
        const float* rr = (const float*)outT;
        int idx = t * 4;
        float4 s = *(const float4*)(rr + idx);
        #pragma unroll
        for (int w2 = 1; w2 < 8; w2++) {
            float4 p = *(const float4*)(rr + w2 * 2048 + idx);
            s.x += p.x; s.y += p.y; s.z += p.z; s.w += p.w;
        }
        *(float4*)(Fpart + (size_t)b * fstride + (size_t)grp * 2048 + idx) = s;
    }
}

// Write one W-matrix value (row 64+kk, col o) into per-b ks2 A-frags (hi+lo).
__device__ __forceinline__ void wfrag(u16* wb2, int mt, int kk, int ol, float val) {
    int lane = ol + (((kk & 15) >> 2) << 4);
    int e = (kk & 3) + ((kk >> 4) << 2);
    u16 h, lo;
    bf16split(val, h, lo);
    wb2[(size_t)mt * 512 + lane * 8 + e] = h;
    wb2[(size_t)(4 + mt) * 512 + lane * 8 + e] = lo;
}

// Mode mix. Phase 1: reduce Fpart[b][0..nblk) into LDS Fs[8][64]. Phase 2:
// P = F*kern, emit spectral A-frags WfA2[b].
__global__ __launch_bounds__(256) void kmix(const float* __restrict__ Fpart,
        const float* __restrict__ kr, const float* __restrict__ ki,
        const float* __restrict__ cb, u16* __restrict__ WfA2, int l,
        int nblk, int fstride) {
    int b = blockIdx.x, kg = blockIdx.y;
    int t = threadIdx.x;
    int o = t & 63, ii = t >> 6;
    __shared__ float Fs[8][64];
    {
        const float* fp = Fpart + (size_t)b * fstride;
        int r0 = t >> 6, oo = t & 63;
        int kc0 = kg * 4 + r0;          // cos rows (Re)
        int kc1 = 16 + kg * 4 + r0;     // sin rows (Im)
        float s0 = 0.f, s1 = 0.f, s2 = 0.f, s3 = 0.f;
        int blk = 0;
        for (; blk + 2 <= nblk; blk += 2) {
            s0 += fp[(size_t)blk * 2048 + kc0 * 64 + oo];
            s1 += fp[(size_t)(blk + 1) * 2048 + kc0 * 64 + oo];
            s2 += fp[(size_t)blk * 2048 + kc1 * 64 + oo];
            s3 += fp[(size_t)(blk + 1) * 2048 + kc1 * 64 + oo];
        }
        if (blk < nblk) {
            s0 += fp[(size_t)blk * 2048 + kc0 * 64 + oo];
            s2 += fp[(size_t)blk * 2048 + kc1 * 64 + oo];
        }
        Fs[r0][oo] = s0 + s1;
        Fs[4 + r0][oo] = s2 + s3;
    }
    __syncthreads();

    const float* krl = kr + (size_t)l * W * W * M;
    const float* kil = ki + (size_t)l * W * W * M;
    float pr[4] = {0.f, 0.f, 0.f, 0.f}, pi[4] = {0.f, 0.f, 0.f, 0.f};
    for (int i = ii * 16; i < ii * 16 + 16; i++) {
        float4 kr4 = *(const float4*)(krl + ((size_t)i * W + o) * M + kg * 4);
        float4 ki4 = *(const float4*)(kil + ((size_t)i * W + o) * M + kg * 4);
        float re0 = Fs[0][i], im0 = Fs[4][i];
        float re1 = Fs[1][i], im1 = Fs[5][i];
        float re2 = Fs[2][i], im2 = Fs[6][i];
        float re3 = Fs[3][i], im3 = Fs[7][i];
        pr[0] += re0 * kr4.x - im0 * ki4.x;  pi[0] += re0 * ki4.x + im0 * kr4.x;
        pr[1] += re1 * kr4.y - im1 * ki4.y;  pi[1] += re1 * ki4.y + im1 * kr4.y;
        pr[2] += re2 * kr4.z - im2 * ki4.z;  pi[2] += re2 * ki4.z + im2 * kr4.z;
        pr[3] += re3 * kr4.w - im3 * ki4.w;  pi[3] += re3 * ki4.w + im3 * kr4.w;
    }
    __shared__ float red[4][64][8];
    #pragma unroll
    for (int c = 0; c < 4; c++) {
        red[ii][o][2 * c]     = pr[c];
        red[ii][o][2 * c + 1] = pi[c];
    }
    __syncthreads();
    if (ii == 0) {
        u16* wb2 = WfA2 + (size_t)b * 4096;
        int mt = o >> 4, ol = o & 15;
        #pragma unroll
        for (int c = 0; c < 4; c++) {
            int k = kg * 4 + c;
            float sr = red[0][o][2 * c] + red[1][o][2 * c] + red[2][o][2 * c] + red[3][o][2 * c];
            float si = red[0][o][2 * c + 1] + red[1][o][2 * c + 1] + red[2][o][2 * c + 1] + red[3][o][2 * c + 1];
            if (k == 0) {
                wfrag(wb2, mt, 30, ol, cb[l * W + o] + sr * (1.0f / (float)NLEN));
                wfrag(wb2, mt, 31, ol, 0.0f);
            } else {
                wfrag(wb2, mt, k - 1,  ol, sr * (2.0f / (float)NLEN));
                wfrag(wb2, mt, 14 + k, ol, -si * (2.0f / (float)NLEN));
            }
        }
    }
}

// Fused conv + inverse transform + gelu via bf16-split MFMA, IN-PLACE, plus
// (dodft) fused forward-DFT of the OUTPUT.
__global__ __launch_bounds__(512, 4) void kconv(float* __restrict__ v,
        const u16* __restrict__ AcwL, const u16* __restrict__ WfA2,
        const u16* __restrict__ Ustat, const u16* __restrict__ Tdft,
        float* __restrict__ Fpart, int fstride, int dodft) {
    __shared__ __align__(16) u16 fragU[2][2][16][64][8];   // 64 KB
    int t = threadIdx.x;
    int b = blockIdx.y;
    int n0 = blockIdx.x * 256;
    int lane = t & 63;
    int wv = __builtin_amdgcn_readfirstlane(t >> 6);       // 0..7
    float* vb = v + (size_t)b * W * SROW;

    {
        int col = t & 255;
        int half = t >> 8;                 // 0/1
        int nt = col >> 4;
        int lt = col & 15;
        #pragma unroll
        for (int q = 0; q < 8; q++) {
            int quad = q * 2 + half;       // 0..15 -> rows 4q..4q+3
            const float* src = vb + (size_t)(quad * 4) * SROW + n0 + col;
            float x0 = src[0];
            float x1 = src[SROW];
            float x2 = src[2 * SROW];
            float x3 = src[3 * SROW];
            int ks = quad >> 3;
            int laneT = lt + ((quad & 3) << 4);
            int e0 = ((quad >> 2) & 1) << 2;
            u16 h0, l0, h1, l1, h2, l2, h3, l3;
            bf16split(x0, h0, l0); bf16split(x1, h1, l1);
            bf16split(x2, h2, l2); bf16split(x3, h3, l3);
            short4v hv = {(short)h0, (short)h1, (short)h2, (short)h3};
            short4v lv = {(short)l0, (short)l1, (short)l2, (short)l3};
            *(short4v*)&fragU[ks][0][nt][laneT][e0] = hv;
            *(short4v*)&fragU[ks][1][nt][laneT][e0] = lv;
        }
    }

    f32x4 acc[4][2];
    #pragma unroll
    for (int mt = 0; mt < 4; mt++)
        #pragma unroll
        for (int j = 0; j < 2; j++)
            acc[mt][j] = (f32x4){0.f, 0.f, 0.f, 0.f};

    __syncthreads();

    const u16* wb2 = WfA2 + (size_t)b * 4096;
    int nt0 = wv * 2;
    #pragma unroll
    for (int ks = 0; ks < 3; ks++) {
        const u16* ab = (ks < 2) ? (AcwL + (size_t)ks * 4096) : wb2;
        bf16x8 Ah[4], Al[4];
        #pragma unroll
        for (int mt = 0; mt < 4; mt++) {
            Ah[mt] = *(const bf16x8*)(ab + (size_t)mt * 512 + lane * 8);
            Al[mt] = *(const bf16x8*)(ab + (size_t)(4 + mt) * 512 + lane * 8);
        }
        #pragma unroll
        for (int ntl = 0; ntl < 2; ntl++) {
            bf16x8 Bh, Bl;
            if (ks < 2) {
                Bh = *(const bf16x8*)&fragU[ks][0][nt0 + ntl][lane][0];
                Bl = *(const bf16x8*)&fragU[ks][1][nt0 + ntl][lane][0];
            } else {
                int ntg = (n0 >> 4) + nt0 + ntl;
                if (ntg >= NT_STAT) ntg = NT_STAT - 1;   // OOB cols: finite junk
                Bh = *(const bf16x8*)(Ustat + ((size_t)ntg * 64 + lane) * 8);
                Bl = *(const bf16x8*)(Ustat + (size_t)NT_STAT * 512 + ((size_t)ntg * 64 + lane) * 8);
            }
            #pragma unroll
            for (int mt = 0; mt < 4; mt++) {
                acc[mt][ntl] = __builtin_amdgcn_mfma_f32_16x16x32_bf16(Ah[mt], Bh, acc[mt][ntl], 0, 0, 0);
                acc[mt][ntl] = __builtin_amdgcn_mfma_f32_16x16x32_bf16(Ah[mt], Bl, acc[mt][ntl], 0, 0, 0);
                acc[mt][ntl] = __builtin_amdgcn_mfma_f32_16x16x32_bf16(Al[mt], Bh, acc[mt][ntl], 0, 0, 0);
                acc[mt][ntl] = __builtin_amdgcn_mfma_f32_16x16x32_bf16(Al[mt], Bl, acc[mt][ntl], 0, 0, 0);
            }
        }
    }

    int r4 = (lane >> 4) << 2;
    #pragma unroll
    for (int ntl = 0; ntl < 2; ntl++) {
        int n = n0 + wv * 32 + ntl * 16 + (lane & 15);
        #pragma unroll
        for (int mt = 0; mt < 4; mt++) {
            acc[mt][ntl][0] = gelu_f(acc[mt][ntl][0]);
            acc[mt][ntl][1] = gelu_f(acc[mt][ntl][1]);
            acc[mt][ntl][2] = gelu_f(acc[mt][ntl][2]);
            acc[mt][ntl][3] = gelu_f(acc[mt][ntl][3]);
        }
        if (n < SROW) {
            #pragma unroll
            for (int mt = 0; mt < 4; mt++) {
                float* vo = vb + (size_t)(mt * 16 + r4) * SROW + n;
                vo[0]        = acc[mt][ntl][0];
                vo[SROW]     = acc[mt][ntl][1];
                vo[2 * SROW] = acc[mt][ntl][2];
                vo[3 * SROW] = acc[mt][ntl][3];
            }
        }
    }

    if (dodft) {
        __syncthreads();                       // all waves done reading fragU
        u16* outW = ((u16*)fragU) + wv * 4096; // per-wave region, self-only
        int nbase = n0 + wv * 32;
        #pragma unroll
        for (int ntl = 0; ntl < 2; ntl++) {
            int nl = ntl * 16 + (lane & 15);
            bool ok = (nbase + nl) <= 8200;    // DFT covers n in [0,8200]
            #pragma unroll
            for (int mt = 0; mt < 4; mt++) {
                #pragma unroll
                for (int j = 0; j < 4; j++) {
                    int oo = mt * 16 + r4 + j;
                    float gv = ok ? acc[mt][ntl][j] : 0.f;
                    u16 h, lo;
                    bf16split(gv, h, lo);
                    int raw = oo * 128 + nl * 2;
                    int swz = (oo & 7) << 4;
                    outW[(raw ^ swz) >> 1] = h;
                    outW[((raw + 64) ^ swz) >> 1] = lo;
                }
            }
        }
        int nstep = (n0 >> 5) + wv;
        if (nstep > NSTEPS - 1) nstep = NSTEPS - 1;
        const u16* at = Tdft + (size_t)nstep * 2048;
        bf16x8 Th0 = *(const bf16x8*)(at + lane * 8);
        bf16x8 Tl0 = *(const bf16x8*)(at + 512 + lane * 8);
        bf16x8 Th1 = *(const bf16x8*)(at + 1024 + lane * 8);
        bf16x8 Tl1 = *(const bf16x8*)(at + 1536 + lane * 8);
        f32x4 dacc[2][4];
        #pragma unroll
        for (int kt = 0; kt < 2; kt++)
            #pragma unroll
            for (int ot = 0; ot < 4; ot++) dacc[kt][ot] = (f32x4){0.f, 0.f, 0.f, 0.f};
        int g = lane >> 4;
        #pragma unroll
        for (int ot = 0; ot < 4; ot++) {
            int oo = ot * 16 + (lane & 15);
            int swz = (oo & 7) << 4;
            bf16x8 Bh = *(const bf16x8*)(outW + (((oo * 128 + g * 16) ^ swz) >> 1));
            bf16x8 Bl = *(const bf16x8*)(outW + (((oo * 128 + 64 + g * 16) ^ swz) >> 1));
            dacc[0][ot] = __builtin_amdgcn_mfma_f32_16x16x32_bf16(Th0, Bh, dacc[0][ot], 0, 0, 0);
            dacc[0][ot] = __builtin_amdgcn_mfma_f32_16x16x32_bf16(Th0, Bl, dacc[0][ot], 0, 0, 0);
            dacc[0][ot] = __builtin_amdgcn_mfma_f32_16x16x32_bf16(Tl0, Bh, dacc[0][ot], 0, 0, 0);
            dacc[0][ot] = __builtin_amdgcn_mfma_f32_16x16x32_bf16(Tl0, Bl, dacc[0][ot], 0, 0, 0);
            dacc[1][ot] = __builtin_amdgcn_mfma_f32_16x16x32_bf16(Th1, Bh, dacc[1][ot], 0, 0, 0);
            dacc[1][ot] = __builtin_amdgcn_mfma_f32_16x16x32_bf16(Th1, Bl, dacc[1][ot], 0, 0, 0);
            dacc[1][ot] = __builtin_amdgcn_mfma_f32_16x16x32_bf16(Tl1, Bh, dacc[1][ot], 0, 0, 0);
            dacc[1][ot] = __builtin_amdgcn_mfma_f32_16x16x32_bf16(Tl1, Bl, dacc[1][ot], 0, 0, 0);
        }
        float* rw = (float*)fragU + wv * 2048;
        #pragma unroll
        for (int kt = 0; kt < 2; kt++)
            #pragma unroll
            for (int ot = 0; ot < 4; ot++) {
                int oo = ot * 16 + (lane & 15);
                int kcb = kt * 16 + ((lane >> 4) << 2);
                rw[(kcb + 0) * 64 + oo] = dacc[kt][ot][0];
                rw[(kcb + 1) * 64 + oo] = dacc[kt][ot][1];
                rw[(kcb + 2) * 64 + oo] = dacc[kt][ot][2];
                rw[(kcb + 3) * 64 + oo] = dacc[kt][ot][3];
            }
        __syncthreads();
        {
            const float* rr = (const float*)fragU;
            int idx = t * 4;
            float4 s = *(const float4*)(rr + idx);
            #pragma unroll
            for (int w2 = 1; w2 < 8; w2++) {
                float4 p = *(const float4*)(rr + w2 * 2048 + idx);
                s.x += p.x; s.y += p.y; s.z += p.z; s.w += p.w;
            }
            *(float4*)(Fpart + (size_t)b * fstride + (size_t)blockIdx.x * 2048 + idx) = s;
        }
    }
}

// MFMA projection: out[b][n] = gelu(v(:,n)^T W1 + b1) . w2 + b2.
// Per block: 128h x 256n via bf16-split MFMA; register-only epilogue with
// shfl_xor cross-lane reduce (lanes 16 apart hold different h, same n).
__global__ __launch_bounds__(512, 4) void kproj2(const float* __restrict__ v,
        const u16* __restrict__ Aw1, const float* __restrict__ b1,
        const float* __restrict__ w2, const float* __restrict__ b2,
        float* __restrict__ out) {
    __shared__ __align__(16) u16 fragU[2][2][16][64][8];   // 64 KB
    int t = threadIdx.x;
    int b = blockIdx.y;
    int n0 = blockIdx.x * 256;   // 32 blocks x 256 = 8192 exact
    int lane = t & 63;
    int wv = __builtin_amdgcn_readfirstlane(t >> 6);
    const float* vb = v + (size_t)b * W * SROW;

    {   // stage v rows 0..63 x 256 cols as bf16 hi/lo frags (same as kconv)
        int col = t & 255;
        int half = t >> 8;
        int nt = col >> 4;
        int lt = col & 15;
        #pragma unroll
        for (int q = 0; q < 8; q++) {
            int quad = q * 2 + half;
            const float* src = vb + (size_t)(quad * 4) * SROW + n0 + col;
            float x0 = src[0];
            float x1 = src[SROW];
            float x2 = src[2 * SROW];
            float x3 = src[3 * SROW];
            int ks = quad >> 3;
            int laneT = lt + ((quad & 3) << 4);
            int e0 = ((quad >> 2) & 1) << 2;
            u16 h0, l0, h1, l1, h2, l2, h3, l3;
            bf16split(x0, h0, l0); bf16split(x1, h1, l1);
            bf16split(x2, h2, l2); bf16split(x3, h3, l3);
            short4v hv = {(short)h0, (short)h1, (short)h2, (short)h3};
            short4v lv = {(short)l0, (short)l1, (short)l2, (short)l3};
            *(short4v*)&fragU[ks][0][nt][laneT][e0] = hv;
            *(short4v*)&fragU[ks][1][nt][laneT][e0] = lv;
        }
    }

    int r4 = (lane >> 4) << 2;
    f32x4 acc[8][2];
    #pragma unroll
    for (int mt = 0; mt < 8; mt++) {
        #pragma unroll
        for (int j = 0; j < 4; j++) {
            float bs = b1[mt * 16 + r4 + j];
            acc[mt][0][j] = bs;
            acc[mt][1][j] = bs;
        }
    }
    __syncthreads();

    int nt0 = wv * 2;
    #pragma unroll
    for (int ks = 0; ks < 2; ks++) {
        bf16x8 Bh[2], Bl[2];
        #pragma unroll
        for (int ntl = 0; ntl < 2; ntl++) {
            Bh[ntl] = *(const bf16x8*)&fragU[ks][0][nt0 + ntl][lane][0];
            Bl[ntl] = *(const bf16x8*)&fragU[ks][1][nt0 + ntl][lane][0];
        }
        #pragma unroll
        for (int mt = 0; mt < 8; mt++) {
            bf16x8 Ah = *(const bf16x8*)(Aw1 + (((size_t)ks * 2 + 0) * 8 + mt) * 512 + lane * 8);
            bf16x8 Al = *(const bf16x8*)(Aw1 + (((size_t)ks * 2 + 1) * 8 + mt) * 512 + lane * 8);
            #pragma unroll
            for (int ntl = 0; ntl < 2; ntl++) {
                acc[mt][ntl] = __builtin_amdgcn_mfma_f32_16x16x32_bf16(Ah, Bh[ntl], acc[mt][ntl], 0, 0, 0);
                acc[mt][ntl] = __builtin_amdgcn_mfma_f32_16x16x32_bf16(Ah, Bl[ntl], acc[mt][ntl], 0, 0, 0);
                acc[mt][ntl] = __builtin_amdgcn_mfma_f32_16x16x32_bf16(Al, Bh[ntl], acc[mt][ntl], 0, 0, 0);
                acc[mt][ntl] = __builtin_amdgcn_mfma_f32_16x16x32_bf16(Al, Bl[ntl], acc[mt][ntl], 0, 0, 0);
            }
        }
    }

    // epilogue: p(n) = sum_h gelu(h)*w2[h]; reduce across lane-groups (h-quads)
    float bb = b2[0];
    #pragma unroll
    for (int ntl = 0; ntl < 2; ntl++) {
        float p = 0.f;
        #pragma unroll
        for (int mt = 0; mt < 8; mt++) {
            p = fmaf(gelu_f(acc[mt][ntl][0]), w2[mt * 16 + r4 + 0], p);
            p = fmaf(gelu_f(acc[mt][ntl][1]), w2[mt * 16 + r4 + 1], p);
            p = fmaf(gelu_f(acc[mt][ntl][2]), w2[mt * 16 + r4 + 2], p);
            p = fmaf(gelu_f(acc[mt][ntl][3]), w2[mt * 16 + r4 + 3], p);
        }
        p += __shfl_xor(p, 16, 64);
        p += __shfl_xor(p, 32, 64);
        if (lane < 16) {
            int n = n0 + wv * 32 + ntl * 16 + lane;
            out[(size_t)b * 8192 + n] = p + bb;
        }
    }
}

extern "C" void kernel_launch(void* const* d_in, const int* in_sizes, int n_in,
                              void* d_out, int out_size, void* d_ws, size_t ws_size,
                              hipStream_t stream) {
    const float* x  = (const float*)d_in[0];
    const float* lw = (const float*)d_in[1];
    const float* lb = (const float*)d_in[2];
    const float* kr = (const float*)d_in[3];
    const float* ki = (const float*)d_in[4];
    const float* cw = (const float*)d_in[5];
    const float* cb = (const float*)d_in[6];
    const float* w1 = (const float*)d_in[7];
    const float* b1 = (const float*)d_in[8];
    const float* w2 = (const float*)d_in[9];
    const float* b2 = (const float*)d_in[10];
    float* out = (float*)d_out;

    float* ws = (float*)d_ws;
    size_t vsz = (size_t)NB * W * SROW;
    float* v    = ws;
    u16* Ustat  = (u16*)(v + vsz);
    u16* AcwBuf = Ustat + (size_t)2 * NT_STAT * 512;
    u16* WfA2   = AcwBuf + (size_t)NL * 8192;
    u16* Tdft   = WfA2 + (size_t)NB * 4096;
    u16* Aw1    = Tdft + (size_t)NSTEPS * 2048;
    size_t u16_total = (size_t)2 * NT_STAT * 512 + (size_t)NL * 8192
                     + (size_t)NB * 4096 + (size_t)NSTEPS * 2048 + 16384;
    size_t fpart_off = vsz + u16_total / 2;          // u16_total is even
    float* Fpart = ws + fpart_off;
    size_t need_fused = (fpart_off + (size_t)NB * 33 * 2048) * sizeof(float);
    int fused = (ws_size >= need_fused) ? 1 : 0;
    int fstride = fused ? (33 * 2048) : (4 * 2048);

    kstat<<<dim3(NT_STAT), 256, 0, stream>>>(Ustat);
    kdtab<<<dim3(NSTEPS), 256, 0, stream>>>(Tdft);
    kprep<<<dim3(NL), 256, 0, stream>>>(cw, AcwBuf);
    kprep2<<<dim3(1), 256, 0, stream>>>(w1, Aw1);

    if (fused) {
        klift2<<<dim3(33, NB), 512, 0, stream>>>(x, lw, lb, v, Tdft, Fpart, fstride);
        for (int l = 0; l < NL; l++) {
            kmix<<<dim3(NB, 4), 256, 0, stream>>>(Fpart, kr, ki, cb, WfA2, l,
                                                  33, fstride);
            kconv<<<dim3(33, NB), 512, 0, stream>>>(v, AcwBuf + (size_t)l * 8192,
                    WfA2, Ustat, Tdft, Fpart, fstride, (l < NL - 1) ? 1 : 0);
        }
    } else {
        klift<<<dim3(9, NB), 256, 0, stream>>>(x, lw, lb, v);
        for (int l = 0; l < NL; l++) {
            kdft2<<<dim3(NB, 4), 512, 0, stream>>>(v, Tdft, Fpart, fstride);
            kmix<<<dim3(NB, 4), 256, 0, stream>>>(Fpart, kr, ki, cb, WfA2, l,
                                                  4, fstride);
            kconv<<<dim3(33, NB), 512, 0, stream>>>(v, AcwBuf + (size_t)l * 8192,
                    WfA2, Ustat, Tdft, Fpart, fstride, 0);
        }
    }
    kproj2<<<dim3(32, NB), 512, 0, stream>>>(v, Aw1, b1, w2, b2, out);
}